// Round 1
// baseline (2711.380 us; speedup 1.0000x reference)
//
#include <hip/hip_runtime.h>
#include <hip/hip_bf16.h>

#define EPSV 1e-5f

// ---------------------------------------------------------------------------
// Generic fp32 NT GEMM: C[M,Nout] = A[M,K] @ B[Nout,K]^T  (+ optional A2@B2^T)
// EPI: 0 = +bias[col]; 1 = relu(+bias[col]); 2 = BN epilogue (b,g,be,m,v)
// ACCUM: C += result (EPI 0 only in practice)
// storeN: number of columns actually stored (cols in [Nout,storeN) get 0)
// Requires K % 16 == 0, lda/ldb multiples of 4, 16B-aligned base pointers.
// ---------------------------------------------------------------------------
template <int EPI, bool ACCUM, bool DUAL>
__global__ __launch_bounds__(256) void gemm_nt(
    const float* __restrict__ A, int lda, const float* __restrict__ B, int ldb,
    const float* __restrict__ A2, const float* __restrict__ B2,
    float* __restrict__ C, int ldc, int M, int Nout, int K, int storeN,
    const float* __restrict__ bias, const float* __restrict__ bnb,
    const float* __restrict__ bng, const float* __restrict__ bnbe,
    const float* __restrict__ bnm, const float* __restrict__ bnv) {
  constexpr int DB = DUAL ? 16 : 1;
  __shared__ float As[16][68];
  __shared__ float Bs[16][68];
  __shared__ float As2[DB][68];
  __shared__ float Bs2[DB][68];

  const int tid = threadIdx.x;
  const int tx = tid & 15;   // col group
  const int ty = tid >> 4;   // row group
  const int row0 = blockIdx.x * 64;
  const int col0 = blockIdx.y * 64;

  float acc[4][4];
#pragma unroll
  for (int i = 0; i < 4; ++i)
#pragma unroll
    for (int j = 0; j < 4; ++j) acc[i][j] = 0.f;

  const int r = tid >> 2;        // 0..63 staging row
  const int kq = (tid & 3) * 4;  // 0,4,8,12
  const int ar = min(row0 + r, M - 1);
  const int br = min(col0 + r, Nout - 1);

  const int ksteps = K >> 4;
  for (int kt = 0; kt < ksteps; ++kt) {
    const int kb = kt * 16 + kq;
    float4 av = *(const float4*)&A[(size_t)ar * lda + kb];
    float4 bv = *(const float4*)&B[(size_t)br * ldb + kb];
    float4 av2, bv2;
    if (DUAL) {
      av2 = *(const float4*)&A2[(size_t)ar * lda + kb];
      bv2 = *(const float4*)&B2[(size_t)br * ldb + kb];
    }
    __syncthreads();
    As[kq + 0][r] = av.x; As[kq + 1][r] = av.y; As[kq + 2][r] = av.z; As[kq + 3][r] = av.w;
    Bs[kq + 0][r] = bv.x; Bs[kq + 1][r] = bv.y; Bs[kq + 2][r] = bv.z; Bs[kq + 3][r] = bv.w;
    if (DUAL) {
      As2[kq + 0][r] = av2.x; As2[kq + 1][r] = av2.y; As2[kq + 2][r] = av2.z; As2[kq + 3][r] = av2.w;
      Bs2[kq + 0][r] = bv2.x; Bs2[kq + 1][r] = bv2.y; Bs2[kq + 2][r] = bv2.z; Bs2[kq + 3][r] = bv2.w;
    }
    __syncthreads();
#pragma unroll
    for (int k = 0; k < 16; ++k) {
      float4 a = *(const float4*)&As[k][ty * 4];
      float4 b = *(const float4*)&Bs[k][tx * 4];
      const float aa[4] = {a.x, a.y, a.z, a.w};
      const float bb[4] = {b.x, b.y, b.z, b.w};
#pragma unroll
      for (int i = 0; i < 4; ++i)
#pragma unroll
        for (int j = 0; j < 4; ++j) acc[i][j] = fmaf(aa[i], bb[j], acc[i][j]);
      if (DUAL) {
        float4 a2 = *(const float4*)&As2[k][ty * 4];
        float4 b2 = *(const float4*)&Bs2[k][tx * 4];
        const float aa2[4] = {a2.x, a2.y, a2.z, a2.w};
        const float bb2[4] = {b2.x, b2.y, b2.z, b2.w};
#pragma unroll
        for (int i = 0; i < 4; ++i)
#pragma unroll
          for (int j = 0; j < 4; ++j) acc[i][j] = fmaf(aa2[i], bb2[j], acc[i][j]);
      }
    }
  }

  const int rbase = row0 + ty * 4;
  const int cbase = col0 + tx * 4;
#pragma unroll
  for (int i = 0; i < 4; ++i) {
    const int row = rbase + i;
    if (row >= M) continue;
#pragma unroll
    for (int j = 0; j < 4; ++j) {
      const int col = cbase + j;
      if (col >= storeN) continue;
      float v;
      if (col < Nout) {
        v = acc[i][j];
        if (EPI == 2) {
          const float sc = bng[col] * rsqrtf(bnv[col] + EPSV);
          v = v * sc + (bnb[col] - bnm[col]) * sc + bnbe[col];
        } else {
          v += bias[col];
          if (EPI == 1) v = fmaxf(v, 0.f);
        }
      } else {
        v = 0.f;
      }
      const size_t idx = (size_t)row * ldc + col;
      if (ACCUM) v += C[idx];
      C[idx] = v;
    }
  }
}

// ---------------------------------------------------------------------------
// Combine encoder layer2 (Linear+BN) and decoder Linear into one [64,512]
// weight (k-padded to 512 with zeros) and a 64-bias; folds the 0.5 modality
// mean in. Wc[o][k] = 0.5 * sum_j Wd[o,j]*s2[j]*W2[j,k],
// cc[o] = 0.5*(bd[o] + sum_j Wd[o,j]*((b2[j]-m2[j])*s2[j]+be2[j]))
// ---------------------------------------------------------------------------
__global__ __launch_bounds__(256) void combine_wc(
    const float* __restrict__ W2, const float* __restrict__ b2,
    const float* __restrict__ g2, const float* __restrict__ be2,
    const float* __restrict__ m2, const float* __restrict__ v2,
    const float* __restrict__ Wd, const float* __restrict__ bd,
    float* __restrict__ Wc, float* __restrict__ cc) {
  const int o = blockIdx.y;
  const int k = blockIdx.x * 256 + threadIdx.x;
  __shared__ float t2[128];
  if (threadIdx.x < 128) {
    const int j = threadIdx.x;
    const float s = g2[j] * rsqrtf(v2[j] + EPSV);
    t2[j] = Wd[o * 128 + j] * s;
  }
  __syncthreads();
  if (k < 512) {
    float accv = 0.f;
    if (k < 500) {
      for (int j = 0; j < 128; ++j) accv += t2[j] * W2[j * 500 + k];
      accv *= 0.5f;
    }
    Wc[o * 512 + k] = accv;
  }
  if (blockIdx.x == 0 && threadIdx.x == 0) {
    float accv = bd[o];
    for (int j = 0; j < 128; ++j) {
      const float s = g2[j] * rsqrtf(v2[j] + EPSV);
      accv += Wd[o * 128 + j] * ((b2[j] - m2[j]) * s + be2[j]);
    }
    cc[o] = 0.5f * accv;
  }
}

// ---------------------------------------------------------------------------
// Edge scatter-max: agg[dst][f] = max(agg[dst][f], m[src][f]). m >= 0 (post
// relu) so non-negative float bits order as uints; agg pre-zeroed handles
// isolated nodes (DGL -inf -> 0 semantics).
// ---------------------------------------------------------------------------
__global__ __launch_bounds__(256) void edge_max(const float* __restrict__ m,
                                                const int* __restrict__ src,
                                                const int* __restrict__ dst,
                                                unsigned int* __restrict__ agg,
                                                int ne) {
  const int e = blockIdx.x * 4 + (threadIdx.x >> 6);
  const int f = threadIdx.x & 63;
  if (e < ne) {
    const int s = src[e];
    const int d = dst[e];
    const float v = m[(size_t)s * 64 + f];
    atomicMax(&agg[(size_t)d * 64 + f], __float_as_uint(v));
  }
}

extern "C" void kernel_launch(void* const* d_in, const int* in_sizes, int n_in,
                              void* d_out, int out_size, void* d_ws,
                              size_t ws_size, hipStream_t stream) {
  const int N = 100000;
  const int NE = in_sizes[2];  // 1200000 edges

  const float* x0 = (const float*)d_in[0];
  const float* x1 = (const float*)d_in[1];
  const int* src = (const int*)d_in[2];
  const int* dst = (const int*)d_in[3];

  // encoder params: base 4 (enc0) and 18 (enc1)
  auto F = [&](int i) { return (const float*)d_in[i]; };
  // sage params: s0@32, s1@37, s2@42 : Wp, bp, Ws, Wn, b

  // workspace carve-up
  char* wsb = (char*)d_ws;
  size_t off = 0;
  auto alloc = [&](size_t bytes) {
    void* p = wsb + off;
    off += (bytes + 255) & ~(size_t)255;
    return p;
  };
  float* Wc0 = (float*)alloc(64 * 512 * 4);
  float* Wc1 = (float*)alloc(64 * 512 * 4);
  float* cc0 = (float*)alloc(64 * 4);
  float* cc1 = (float*)alloc(64 * 4);
  const int CH = 12800;  // encoder row chunk (multiple of 64)
  float* E = (float*)alloc((size_t)CH * 512 * 4);
  float* feat = (float*)alloc((size_t)N * 64 * 4);
  float* mbuf = (float*)alloc((size_t)N * 64 * 4);
  float* agg = (float*)alloc((size_t)N * 64 * 4);
  float* h1 = (float*)alloc((size_t)N * 64 * 4);
  float* h2 = (float*)alloc((size_t)N * 64 * 4);
  (void)ws_size;

  // 1) combined layer2+decoder weights per modality
  combine_wc<<<dim3(2, 64), 256, 0, stream>>>(F(10), F(11), F(12), F(13), F(14),
                                              F(15), F(16), F(17), Wc0, cc0);
  combine_wc<<<dim3(2, 64), 256, 0, stream>>>(F(24), F(25), F(26), F(27), F(28),
                                              F(29), F(30), F(31), Wc1, cc1);

  // 2) encoders, chunked over rows: E = BN(x @ W1^T + b1); feat (+)= E @ Wc^T + cc
  for (int r0 = 0; r0 < N; r0 += CH) {
    const int mr = min(CH, N - r0);
    dim3 g1((mr + 63) / 64, 8);
    gemm_nt<2, false, false><<<g1, 256, 0, stream>>>(
        x0 + (size_t)r0 * 512, 512, F(4), 512, nullptr, nullptr, E, 512, mr,
        500, 512, 512, nullptr, F(5), F(6), F(7), F(8), F(9));
    dim3 g2((mr + 63) / 64, 1);
    gemm_nt<0, false, false><<<g2, 256, 0, stream>>>(
        E, 512, Wc0, 512, nullptr, nullptr, feat + (size_t)r0 * 64, 64, mr, 64,
        512, 64, cc0, nullptr, nullptr, nullptr, nullptr, nullptr);
  }
  for (int r0 = 0; r0 < N; r0 += CH) {
    const int mr = min(CH, N - r0);
    dim3 g1((mr + 63) / 64, 8);
    gemm_nt<2, false, false><<<g1, 256, 0, stream>>>(
        x1 + (size_t)r0 * 256, 256, F(18), 256, nullptr, nullptr, E, 512, mr,
        500, 256, 512, nullptr, F(19), F(20), F(21), F(22), F(23));
    dim3 g2((mr + 63) / 64, 1);
    gemm_nt<0, true, false><<<g2, 256, 0, stream>>>(
        E, 512, Wc1, 512, nullptr, nullptr, feat + (size_t)r0 * 64, 64, mr, 64,
        512, 64, cc1, nullptr, nullptr, nullptr, nullptr, nullptr);
  }

  // 3) three SAGE-pool layers
  const dim3 gm((N + 63) / 64, 1);
  const int eblocks = (NE + 3) / 4;
  auto sage = [&](const float* hin, int pbase, float* hout, int o, bool relu_out) {
    const float* Wp = F(pbase + 0);
    const float* bp = F(pbase + 1);
    const float* Ws = F(pbase + 2);
    const float* Wn = F(pbase + 3);
    const float* bb = F(pbase + 4);
    // m = relu(hin @ Wp^T + bp)
    gemm_nt<1, false, false><<<gm, 256, 0, stream>>>(
        hin, 64, Wp, 64, nullptr, nullptr, mbuf, 64, N, 64, 64, 64, bp, nullptr,
        nullptr, nullptr, nullptr, nullptr);
    hipMemsetAsync(agg, 0, (size_t)N * 64 * 4, stream);
    edge_max<<<eblocks, 256, 0, stream>>>(mbuf, src, dst, (unsigned int*)agg, NE);
    // hout = [relu](hin @ Ws^T + agg @ Wn^T + b)
    dim3 go((N + 63) / 64, (o + 63) / 64);
    if (relu_out)
      gemm_nt<1, false, true><<<go, 256, 0, stream>>>(
          hin, 64, Ws, 64, agg, Wn, hout, o, N, o, 64, o, bb, nullptr, nullptr,
          nullptr, nullptr, nullptr);
    else
      gemm_nt<0, false, true><<<go, 256, 0, stream>>>(
          hin, 64, Ws, 64, agg, Wn, hout, o, N, o, 64, o, bb, nullptr, nullptr,
          nullptr, nullptr, nullptr);
  };
  sage(feat, 32, h1, 64, true);
  sage(h1, 37, h2, 64, true);
  sage(h2, 42, (float*)d_out, 8, false);
  (void)out_size; (void)n_in;
}

// Round 3
// 1114.338 us; speedup vs baseline: 2.4332x; 2.4332x over previous
//
#include <hip/hip_runtime.h>
#include <hip/hip_bf16.h>

#define EPSV 1e-5f
using u16 = unsigned short;
typedef __attribute__((ext_vector_type(8))) short short8;
typedef __attribute__((ext_vector_type(4))) float f32x4;

__device__ __forceinline__ u16 f2bf(float f) {
  __hip_bfloat16 h = __float2bfloat16(f);
  u16 u; __builtin_memcpy(&u, &h, 2); return u;
}

__device__ __forceinline__ void gload16(const void* g, void* l) {
  __builtin_amdgcn_global_load_lds(
      (const __attribute__((address_space(1))) void*)g,
      (__attribute__((address_space(3))) void*)l, 16, 0, 0);
}

// fp32 -> bf16 elementwise (n % 4 == 0)
__global__ __launch_bounds__(256) void f2b_k(const float* __restrict__ in,
                                             u16* __restrict__ out, int n) {
  const int stride4 = gridDim.x * blockDim.x * 4;
  for (int i4 = (blockIdx.x * blockDim.x + threadIdx.x) * 4; i4 < n; i4 += stride4) {
    float4 f = *(const float4*)&in[i4];
    ushort4 o;
    o.x = f2bf(f.x); o.y = f2bf(f.y); o.z = f2bf(f.z); o.w = f2bf(f.w);
    *(ushort4*)&out[i4] = o;
  }
}

// ---------------------------------------------------------------------------
// bf16 MFMA NT GEMM: C[M,Nout] = A[M,K] @ B[Nout,K]^T (+ A2@B2^T if DUAL)
// BM=128, BK=64, 256 threads = 4 waves (2x2), wave tile 64 x (BN/2).
// EPI: 0 = +bias; 1 = relu(+bias); 2 = BN epilogue.
// storeN: cols in [Nout,storeN) get 0 (zero-padding). K % 64 == 0.
// LDS XOR-swizzle (T2): slot ^= row&7, applied on pre-swizzled global source
// (global_load_lds writes linearly) and on the ds_read side (rule 21).
// ---------------------------------------------------------------------------
template <int BN, int EPI, bool DUAL, bool ACCUM, typename OUT>
__global__ __launch_bounds__(256) void gemm_mfma(
    const u16* __restrict__ A, int lda, const u16* __restrict__ B, int ldb,
    const u16* __restrict__ A2, const u16* __restrict__ B2, void* __restrict__ C,
    int ldc, int M, int Nout, int K, int storeN, const float* __restrict__ bias,
    const float* __restrict__ bnb, const float* __restrict__ bng,
    const float* __restrict__ bnbe, const float* __restrict__ bnm,
    const float* __restrict__ bnv) {
  constexpr int WN = BN / 2;   // 64 or 32
  constexpr int NF = WN / 16;  // 4 or 2
  constexpr int MF = 4;
  __shared__ u16 sA[128 * 64];
  __shared__ u16 sB[BN * 64];
  __shared__ u16 sA2[DUAL ? 128 * 64 : 8];
  __shared__ u16 sB2[DUAL ? BN * 64 : 8];

  const int tid = threadIdx.x;
  const int l = tid & 63;
  const int w = tid >> 6;
  const int wm = w >> 1, wn = w & 1;
  const int row0 = blockIdx.x * 128;
  const int col0 = blockIdx.y * BN;

  f32x4 acc[MF][NF];
#pragma unroll
  for (int mf = 0; mf < MF; ++mf)
#pragma unroll
    for (int nf = 0; nf < NF; ++nf) acc[mf][nf] = f32x4{0.f, 0.f, 0.f, 0.f};

  const int srl = l >> 3;  // row within wave's 8-row stage group
  const int ssl = l & 7;   // physical 16B slot

  const int ksteps = K >> 6;
  for (int kt = 0; kt < ksteps; ++kt) {
    const int kb = kt * 64;
    // stage A (128 rows x 64 k): 4 calls of 256x16B
#pragma unroll
    for (int c = 0; c < 4; ++c) {
      const int r = c * 32 + w * 8 + srl;
      const int gr = min(row0 + r, M - 1);
      const int gk = kb + ((ssl ^ (r & 7)) << 3);
      gload16(&A[(size_t)gr * lda + gk], &sA[(c * 32 + w * 8) * 64]);
      if (DUAL) gload16(&A2[(size_t)gr * lda + gk], &sA2[(c * 32 + w * 8) * 64]);
    }
    // stage B (BN rows x 64 k)
#pragma unroll
    for (int c = 0; c < BN / 32; ++c) {
      const int r = c * 32 + w * 8 + srl;
      const int gr = min(col0 + r, Nout - 1);
      const int gk = kb + ((ssl ^ (r & 7)) << 3);
      gload16(&B[(size_t)gr * ldb + gk], &sB[(c * 32 + w * 8) * 64]);
      if (DUAL) gload16(&B2[(size_t)gr * ldb + gk], &sB2[(c * 32 + w * 8) * 64]);
    }
    __syncthreads();
#pragma unroll
    for (int kk = 0; kk < 2; ++kk) {
      short8 af[MF], bfr[NF], af2[MF], bf2[NF];
#pragma unroll
      for (int mf = 0; mf < MF; ++mf) {
        const int r = wm * 64 + mf * 16 + (l & 15);
        const int sl = kk * 4 + (l >> 4);
        const int idx = r * 64 + ((sl ^ (r & 7)) << 3);
        af[mf] = *(const short8*)&sA[idx];
        if (DUAL) af2[mf] = *(const short8*)&sA2[idx];
      }
#pragma unroll
      for (int nf = 0; nf < NF; ++nf) {
        const int r = wn * WN + nf * 16 + (l & 15);
        const int sl = kk * 4 + (l >> 4);
        const int idx = r * 64 + ((sl ^ (r & 7)) << 3);
        bfr[nf] = *(const short8*)&sB[idx];
        if (DUAL) bf2[nf] = *(const short8*)&sB2[idx];
      }
#pragma unroll
      for (int mf = 0; mf < MF; ++mf)
#pragma unroll
        for (int nf = 0; nf < NF; ++nf) {
          acc[mf][nf] = __builtin_amdgcn_mfma_f32_16x16x32_bf16(
              af[mf], bfr[nf], acc[mf][nf], 0, 0, 0);
          if (DUAL)
            acc[mf][nf] = __builtin_amdgcn_mfma_f32_16x16x32_bf16(
                af2[mf], bf2[nf], acc[mf][nf], 0, 0, 0);
        }
    }
    __syncthreads();
  }

  // epilogue: D row=(l>>4)*4+j, col=l&15 (m89-verified)
  const int lj = l >> 4;
  const int lc = l & 15;
#pragma unroll
  for (int mf = 0; mf < MF; ++mf)
#pragma unroll
    for (int nf = 0; nf < NF; ++nf) {
      const int col = col0 + wn * WN + nf * 16 + lc;
      if (col >= storeN) continue;
      const bool cok = col < Nout;
      float sc = 0.f, sh = 0.f;
      if (cok) {
        if (EPI == 2) {
          sc = bng[col] * rsqrtf(bnv[col] + EPSV);
          sh = (bnb[col] - bnm[col]) * sc + bnbe[col];
        } else {
          sh = bias[col];
        }
      }
#pragma unroll
      for (int j = 0; j < 4; ++j) {
        const int row = row0 + wm * 64 + mf * 16 + lj * 4 + j;
        if (row >= M) continue;
        float v = 0.f;
        if (cok) {
          v = acc[mf][nf][j];
          if (EPI == 2) v = v * sc + sh;
          else { v += sh; if (EPI == 1) v = fmaxf(v, 0.f); }
        }
        const size_t idx = (size_t)row * ldc + col;
        if constexpr (sizeof(OUT) == 2) {
          ((u16*)C)[idx] = f2bf(v);
        } else {
          float vv = v;
          if (ACCUM) vv += ((float*)C)[idx];
          ((float*)C)[idx] = vv;
        }
      }
    }
}

// Combined encoder layer2(Linear+BN)+decoder weight [64,512] (k>=500 zero),
// bf16 out; folds the 0.5 modality mean. cc fp32.
__global__ __launch_bounds__(256) void combine_wc(
    const float* __restrict__ W2, const float* __restrict__ b2,
    const float* __restrict__ g2, const float* __restrict__ be2,
    const float* __restrict__ m2, const float* __restrict__ v2,
    const float* __restrict__ Wd, const float* __restrict__ bd,
    u16* __restrict__ Wc, float* __restrict__ cc) {
  const int o = blockIdx.y;
  const int k = blockIdx.x * 256 + threadIdx.x;
  __shared__ float t2[128];
  if (threadIdx.x < 128) {
    const int j = threadIdx.x;
    const float s = g2[j] * rsqrtf(v2[j] + EPSV);
    t2[j] = Wd[o * 128 + j] * s;
  }
  __syncthreads();
  if (k < 512) {
    float accv = 0.f;
    if (k < 500) {
      for (int j = 0; j < 128; ++j) accv += t2[j] * W2[j * 500 + k];
      accv *= 0.5f;
    }
    Wc[o * 512 + k] = f2bf(accv);
  }
  if (blockIdx.x == 0 && threadIdx.x == 0) {
    float accv = bd[o];
    for (int j = 0; j < 128; ++j) {
      const float s = g2[j] * rsqrtf(v2[j] + EPSV);
      accv += Wd[o * 128 + j] * ((b2[j] - m2[j]) * s + be2[j]);
    }
    cc[o] = 0.5f * accv;
  }
}

// ---- CSR build (once per call, reused by all 3 layers) ----
__global__ __launch_bounds__(256) void hist_k(const int* __restrict__ dst,
                                              int* __restrict__ deg, int ne) {
  const int stride = gridDim.x * blockDim.x;
  for (int i = blockIdx.x * blockDim.x + threadIdx.x; i < ne; i += stride)
    atomicAdd(&deg[dst[i]], 1);
}

__global__ __launch_bounds__(1024) void scan_k(const int* __restrict__ deg,
                                               int* __restrict__ rp, int n) {
  __shared__ int lds[1024];
  const int t = threadIdx.x;
  const int Cc = (n + 1023) >> 10;
  const int s = t * Cc, e = min(s + Cc, n);
  int sum = 0;
  for (int i = s; i < e; ++i) sum += deg[i];
  lds[t] = sum;
  __syncthreads();
  for (int off = 1; off < 1024; off <<= 1) {
    int v = (t >= off) ? lds[t - off] : 0;
    __syncthreads();
    lds[t] += v;
    __syncthreads();
  }
  int run = lds[t] - sum;  // exclusive prefix
  for (int i = s; i < e; ++i) { rp[i] = run; run += deg[i]; }
}

// rp is mutated to end-offsets (start = rp[v] - deg[v] afterwards)
__global__ __launch_bounds__(256) void scatter_k(const int* __restrict__ src,
                                                 const int* __restrict__ dst,
                                                 int* __restrict__ rp,
                                                 int* __restrict__ csr, int ne) {
  const int stride = gridDim.x * blockDim.x;
  for (int i = blockIdx.x * blockDim.x + threadIdx.x; i < ne; i += stride) {
    const int p = atomicAdd(&rp[dst[i]], 1);
    csr[p] = src[i];
  }
}

// per-dst max over neighbors; bf16 >=0 compares as u16; init 0 = DGL isolated
__global__ __launch_bounds__(256) void gather_k(
    const u16* __restrict__ m, const int* __restrict__ csr,
    const int* __restrict__ rpend, const int* __restrict__ deg,
    u16* __restrict__ agg, int n) {
  const int v = blockIdx.x * 4 + (threadIdx.x >> 6);
  if (v >= n) return;
  const int l = threadIdx.x & 63;
  const int dg = deg[v];
  const int base = rpend[v] - dg;
  u16 mx = 0;
  for (int i = 0; i < dg; ++i) {
    const int u = csr[base + i];
    const u16 val = m[(size_t)u * 64 + l];
    mx = val > mx ? val : mx;
  }
  agg[(size_t)v * 64 + l] = mx;
}

extern "C" void kernel_launch(void* const* d_in, const int* in_sizes, int n_in,
                              void* d_out, int out_size, void* d_ws,
                              size_t ws_size, hipStream_t stream) {
  const int N = 100000;
  const int NE = in_sizes[2];
  const float* x0 = (const float*)d_in[0];
  const float* x1 = (const float*)d_in[1];
  const int* src = (const int*)d_in[2];
  const int* dst = (const int*)d_in[3];
  auto F = [&](int i) { return (const float*)d_in[i]; };

  char* wsb = (char*)d_ws;
  size_t off = 0;
  auto alloc = [&](size_t bytes) {
    void* p = wsb + off;
    off += (bytes + 255) & ~(size_t)255;
    return p;
  };
  u16* W1b0 = (u16*)alloc(500 * 512 * 2);
  u16* W1b1 = (u16*)alloc(500 * 256 * 2);
  u16* Wc0b = (u16*)alloc(64 * 512 * 2);
  u16* Wc1b = (u16*)alloc(64 * 512 * 2);
  float* cc0 = (float*)alloc(64 * 4);
  float* cc1 = (float*)alloc(64 * 4);
  u16* swb[9];
  const int swsrc[9] = {32, 34, 35, 37, 39, 40, 42, 44, 45};
  const int swn[9] = {4096, 4096, 4096, 4096, 4096, 4096, 4096, 512, 512};
  for (int i = 0; i < 9; ++i) swb[i] = (u16*)alloc(swn[i] * 2);
  const int CH = 25600;
  u16* xb = (u16*)alloc((size_t)CH * 512 * 2);
  u16* E = (u16*)alloc((size_t)CH * 512 * 2);
  float* feat32 = (float*)alloc((size_t)N * 64 * 4);
  u16* featb = (u16*)alloc((size_t)N * 64 * 2);
  u16* mb = (u16*)alloc((size_t)N * 64 * 2);
  u16* aggb = (u16*)alloc((size_t)N * 64 * 2);
  u16* h1b = (u16*)alloc((size_t)N * 64 * 2);
  u16* h2b = (u16*)alloc((size_t)N * 64 * 2);
  int* deg = (int*)alloc((size_t)N * 4);
  int* rp = (int*)alloc((size_t)N * 4);
  int* csr = (int*)alloc((size_t)NE * 4);
  (void)ws_size; (void)n_in;

  // weights -> bf16
  f2b_k<<<64, 256, 0, stream>>>(F(4), W1b0, 500 * 512);
  f2b_k<<<32, 256, 0, stream>>>(F(18), W1b1, 500 * 256);
  for (int i = 0; i < 9; ++i)
    f2b_k<<<4, 256, 0, stream>>>(F(swsrc[i]), swb[i], swn[i]);
  combine_wc<<<dim3(2, 64), 256, 0, stream>>>(F(10), F(11), F(12), F(13), F(14),
                                              F(15), F(16), F(17), Wc0b, cc0);
  combine_wc<<<dim3(2, 64), 256, 0, stream>>>(F(24), F(25), F(26), F(27), F(28),
                                              F(29), F(30), F(31), Wc1b, cc1);

  // CSR build
  hipMemsetAsync(deg, 0, (size_t)N * 4, stream);
  hist_k<<<1024, 256, 0, stream>>>(dst, deg, NE);
  scan_k<<<1, 1024, 0, stream>>>(deg, rp, N);
  scatter_k<<<1024, 256, 0, stream>>>(src, dst, rp, csr, NE);

  // encoders (chunked): E = BN(x@W1^T); feat32 (+)= E @ Wc^T + cc
  for (int c = 0; c < 4; ++c) {
    const int r0 = c * CH;
    const int mr = min(CH, N - r0);
    const int gx = (mr + 127) / 128;
    // modality 0 (K=512)
    f2b_k<<<1024, 256, 0, stream>>>(x0 + (size_t)r0 * 512, xb, mr * 512);
    gemm_mfma<128, 2, false, false, u16><<<dim3(gx, 4), 256, 0, stream>>>(
        xb, 512, W1b0, 512, nullptr, nullptr, E, 512, mr, 500, 512, 512,
        nullptr, F(5), F(6), F(7), F(8), F(9));
    gemm_mfma<64, 0, false, false, float><<<dim3(gx, 1), 256, 0, stream>>>(
        E, 512, Wc0b, 512, nullptr, nullptr, feat32 + (size_t)r0 * 64, 64, mr,
        64, 512, 64, cc0, nullptr, nullptr, nullptr, nullptr, nullptr);
    // modality 1 (K=256)
    f2b_k<<<1024, 256, 0, stream>>>(x1 + (size_t)r0 * 256, xb, mr * 256);
    gemm_mfma<128, 2, false, false, u16><<<dim3(gx, 4), 256, 0, stream>>>(
        xb, 256, W1b1, 256, nullptr, nullptr, E, 512, mr, 500, 256, 512,
        nullptr, F(19), F(20), F(21), F(22), F(23));
    gemm_mfma<64, 0, false, true, float><<<dim3(gx, 1), 256, 0, stream>>>(
        E, 512, Wc1b, 512, nullptr, nullptr, feat32 + (size_t)r0 * 64, 64, mr,
        64, 512, 64, cc1, nullptr, nullptr, nullptr, nullptr, nullptr);
  }
  f2b_k<<<2048, 256, 0, stream>>>(feat32, featb, N * 64);

  // 3 SAGE-pool layers
  const int gx = (N + 127) / 128;
  const int gg = (N + 3) / 4;
  // layer 0
  gemm_mfma<64, 1, false, false, u16><<<dim3(gx, 1), 256, 0, stream>>>(
      featb, 64, swb[0], 64, nullptr, nullptr, mb, 64, N, 64, 64, 64, F(33),
      nullptr, nullptr, nullptr, nullptr, nullptr);
  gather_k<<<gg, 256, 0, stream>>>(mb, csr, rp, deg, aggb, N);
  gemm_mfma<64, 1, true, false, u16><<<dim3(gx, 1), 256, 0, stream>>>(
      featb, 64, swb[1], 64, aggb, swb[2], h1b, 64, N, 64, 64, 64, F(36),
      nullptr, nullptr, nullptr, nullptr, nullptr);
  // layer 1
  gemm_mfma<64, 1, false, false, u16><<<dim3(gx, 1), 256, 0, stream>>>(
      h1b, 64, swb[3], 64, nullptr, nullptr, mb, 64, N, 64, 64, 64, F(38),
      nullptr, nullptr, nullptr, nullptr, nullptr);
  gather_k<<<gg, 256, 0, stream>>>(mb, csr, rp, deg, aggb, N);
  gemm_mfma<64, 1, true, false, u16><<<dim3(gx, 1), 256, 0, stream>>>(
      h1b, 64, swb[4], 64, aggb, swb[5], h2b, 64, N, 64, 64, 64, F(41),
      nullptr, nullptr, nullptr, nullptr, nullptr);
  // layer 2 (C=8, fp32 out, no relu)
  gemm_mfma<64, 1, false, false, u16><<<dim3(gx, 1), 256, 0, stream>>>(
      h2b, 64, swb[6], 64, nullptr, nullptr, mb, 64, N, 64, 64, 64, F(43),
      nullptr, nullptr, nullptr, nullptr, nullptr);
  gather_k<<<gg, 256, 0, stream>>>(mb, csr, rp, deg, aggb, N);
  gemm_mfma<64, 0, true, false, float><<<dim3(gx, 1), 256, 0, stream>>>(
      h2b, 64, swb[7], 64, aggb, swb[8], (float*)d_out, 8, N, 8, 64, 8, F(46),
      nullptr, nullptr, nullptr, nullptr, nullptr);
  (void)out_size;
}

// Round 4
// 731.683 us; speedup vs baseline: 3.7057x; 1.5230x over previous
//
#include <hip/hip_runtime.h>
#include <hip/hip_bf16.h>

#define EPSV 1e-5f
using u16 = unsigned short;
using u32 = unsigned int;
typedef __attribute__((ext_vector_type(8))) short short8;
typedef __attribute__((ext_vector_type(4))) float f32x4;

__device__ __forceinline__ u16 f2bf(float f) {
  __hip_bfloat16 h = __float2bfloat16(f);
  u16 u; __builtin_memcpy(&u, &h, 2); return u;
}

__device__ __forceinline__ void gload16(const void* g, void* l) {
  __builtin_amdgcn_global_load_lds(
      (const __attribute__((address_space(1))) void*)g,
      (__attribute__((address_space(3))) void*)l, 16, 0, 0);
}

// packed 2x u16 max (bf16 >= 0 orders as u16; mask-compare per half)
__device__ __forceinline__ u32 mx2(u32 a, u32 b) {
  u32 ah = a & 0xFFFF0000u, bh = b & 0xFFFF0000u;
  u32 al = a & 0x0000FFFFu, bl = b & 0x0000FFFFu;
  return (ah > bh ? ah : bh) | (al > bl ? al : bl);
}

// ---------------------------------------------------------------------------
// bf16 MFMA NT GEMM: C[M,Nout] = A[M,K] @ B[Nout,K]^T (+ A2@B2^T if DUAL)
// BM=128, BK=64, 256 threads = 4 waves (2x2), wave tile 64 x (BN/2).
// EPI: 0 = +bias; 1 = relu(+bias); 2 = BN epilogue. BIAS2: bias+=bnb[col].
// AF32: A is fp32; reg-staged (load float4 x2, cvt, swizzled ds_write_b128).
// B (and bf16 A) staged via global_load_lds with pre-swizzled global source;
// swizzle (T2): 16B slot ^= row&7, matching on the ds_read side (rule 21).
// storeN: cols in [Nout,storeN) get 0. K % 64 == 0.
// ---------------------------------------------------------------------------
template <int BN, int EPI, bool DUAL, bool AF32, bool BIAS2, typename OUT>
__global__ __launch_bounds__(256) void gemm_mfma(
    const void* __restrict__ A, int lda, const u16* __restrict__ B, int ldb,
    const u16* __restrict__ A2, const u16* __restrict__ B2, void* __restrict__ C,
    int ldc, int M, int Nout, int K, int storeN, const float* __restrict__ bias,
    const float* __restrict__ bnb, const float* __restrict__ bng,
    const float* __restrict__ bnbe, const float* __restrict__ bnm,
    const float* __restrict__ bnv) {
  constexpr int WN = BN / 2;   // 64 or 32
  constexpr int NF = WN / 16;  // 4 or 2
  constexpr int MF = 4;
  __shared__ u16 sA[128 * 64];
  __shared__ u16 sB[BN * 64];
  __shared__ u16 sA2[DUAL ? 128 * 64 : 8];
  __shared__ u16 sB2[DUAL ? BN * 64 : 8];

  const int tid = threadIdx.x;
  const int l = tid & 63;
  const int w = tid >> 6;
  const int wm = w >> 1, wn = w & 1;
  const int row0 = blockIdx.x * 128;
  const int col0 = blockIdx.y * BN;

  f32x4 acc[MF][NF];
#pragma unroll
  for (int mf = 0; mf < MF; ++mf)
#pragma unroll
    for (int nf = 0; nf < NF; ++nf) acc[mf][nf] = f32x4{0.f, 0.f, 0.f, 0.f};

  const int srl = l >> 3;  // row within wave's 8-row stage group
  const int ssl = l & 7;   // 16B slot within row
  const u16* Ab = (const u16*)A;
  const float* Af = (const float*)A;

  const int ksteps = K >> 6;
  for (int kt = 0; kt < ksteps; ++kt) {
    const int kb = kt * 64;
    // ---- stage A (128 rows x 64 k) ----
    if constexpr (AF32) {
      // reg-stage with fp32->bf16: thread r = c*32 + tid>>3, slot = tid&7
      const int ssl2 = tid & 7;
#pragma unroll
      for (int c = 0; c < 4; ++c) {
        const int r = c * 32 + (tid >> 3);
        const int gr = min(row0 + r, M - 1);
        const float* gp = &Af[(size_t)gr * lda + kb + (ssl2 << 3)];
        float4 f0 = *(const float4*)gp;
        float4 f1 = *(const float4*)(gp + 4);
        short8 pk;
        pk[0] = (short)f2bf(f0.x); pk[1] = (short)f2bf(f0.y);
        pk[2] = (short)f2bf(f0.z); pk[3] = (short)f2bf(f0.w);
        pk[4] = (short)f2bf(f1.x); pk[5] = (short)f2bf(f1.y);
        pk[6] = (short)f2bf(f1.z); pk[7] = (short)f2bf(f1.w);
        *(short8*)&sA[r * 64 + ((ssl2 ^ (r & 7)) << 3)] = pk;
      }
    } else {
#pragma unroll
      for (int c = 0; c < 4; ++c) {
        const int r = c * 32 + w * 8 + srl;
        const int gr = min(row0 + r, M - 1);
        const int gk = kb + ((ssl ^ (r & 7)) << 3);
        gload16(&Ab[(size_t)gr * lda + gk], &sA[(c * 32 + w * 8) * 64]);
        if (DUAL) gload16(&A2[(size_t)gr * lda + gk], &sA2[(c * 32 + w * 8) * 64]);
      }
    }
    // ---- stage B (BN rows x 64 k) ----
#pragma unroll
    for (int c = 0; c < BN / 32; ++c) {
      const int r = c * 32 + w * 8 + srl;
      const int gr = min(col0 + r, Nout - 1);
      const int gk = kb + ((ssl ^ (r & 7)) << 3);
      gload16(&B[(size_t)gr * ldb + gk], &sB[(c * 32 + w * 8) * 64]);
      if (DUAL) gload16(&B2[(size_t)gr * ldb + gk], &sB2[(c * 32 + w * 8) * 64]);
    }
    __syncthreads();
#pragma unroll
    for (int kk = 0; kk < 2; ++kk) {
      short8 af[MF], bfr[NF], af2[MF], bf2[NF];
#pragma unroll
      for (int mf = 0; mf < MF; ++mf) {
        const int r = wm * 64 + mf * 16 + (l & 15);
        const int sl = kk * 4 + (l >> 4);
        const int idx = r * 64 + ((sl ^ (r & 7)) << 3);
        af[mf] = *(const short8*)&sA[idx];
        if (DUAL) af2[mf] = *(const short8*)&sA2[idx];
      }
#pragma unroll
      for (int nf = 0; nf < NF; ++nf) {
        const int r = wn * WN + nf * 16 + (l & 15);
        const int sl = kk * 4 + (l >> 4);
        const int idx = r * 64 + ((sl ^ (r & 7)) << 3);
        bfr[nf] = *(const short8*)&sB[idx];
        if (DUAL) bf2[nf] = *(const short8*)&sB2[idx];
      }
#pragma unroll
      for (int mf = 0; mf < MF; ++mf)
#pragma unroll
        for (int nf = 0; nf < NF; ++nf) {
          acc[mf][nf] = __builtin_amdgcn_mfma_f32_16x16x32_bf16(
              af[mf], bfr[nf], acc[mf][nf], 0, 0, 0);
          if (DUAL)
            acc[mf][nf] = __builtin_amdgcn_mfma_f32_16x16x32_bf16(
                af2[mf], bf2[nf], acc[mf][nf], 0, 0, 0);
        }
    }
    __syncthreads();
  }

  // epilogue: D row=(l>>4)*4+j, col=l&15 (m89-verified)
  const int lj = l >> 4;
  const int lc = l & 15;
#pragma unroll
  for (int mf = 0; mf < MF; ++mf)
#pragma unroll
    for (int nf = 0; nf < NF; ++nf) {
      const int col = col0 + wn * WN + nf * 16 + lc;
      if (col >= storeN) continue;
      const bool cok = col < Nout;
      float sc = 0.f, sh = 0.f;
      if (cok) {
        if (EPI == 2) {
          sc = bng[col] * rsqrtf(bnv[col] + EPSV);
          sh = (bnb[col] - bnm[col]) * sc + bnbe[col];
        } else {
          sh = bias[col];
          if (BIAS2) sh += bnb[col];
        }
      }
#pragma unroll
      for (int j = 0; j < 4; ++j) {
        const int row = row0 + wm * 64 + mf * 16 + lj * 4 + j;
        if (row >= M) continue;
        float v = 0.f;
        if (cok) {
          v = acc[mf][nf][j];
          if (EPI == 2) v = v * sc + sh;
          else { v += sh; if (EPI == 1) v = fmaxf(v, 0.f); }
        }
        const size_t idx = (size_t)row * ldc + col;
        if constexpr (sizeof(OUT) == 2) ((u16*)C)[idx] = f2bf(v);
        else ((float*)C)[idx] = v;
      }
    }
}

// ---- merged fp32->bf16 weight conversion (one dispatch for all tensors) ----
struct WConv {
  const float* src[11];
  u16* dst[11];
  int n[11];
};
__global__ __launch_bounds__(256) void wconv_k(WConv wc) {
  const int t = blockIdx.y;
  const float* in = wc.src[t];
  u16* out = wc.dst[t];
  const int n = wc.n[t];
  const int stride4 = gridDim.x * blockDim.x * 4;
  for (int i4 = (blockIdx.x * blockDim.x + threadIdx.x) * 4; i4 < n; i4 += stride4) {
    float4 f = *(const float4*)&in[i4];
    ushort4 o;
    o.x = f2bf(f.x); o.y = f2bf(f.y); o.z = f2bf(f.z); o.w = f2bf(f.w);
    *(ushort4*)&out[i4] = o;
  }
}

// Combined encoder layer2(Linear+BN)+decoder weight [64,512] (k>=500 zero),
// bf16 out; folds the 0.5 modality mean. cc fp32.
__global__ __launch_bounds__(256) void combine_wc(
    const float* __restrict__ W2, const float* __restrict__ b2,
    const float* __restrict__ g2, const float* __restrict__ be2,
    const float* __restrict__ m2, const float* __restrict__ v2,
    const float* __restrict__ Wd, const float* __restrict__ bd,
    u16* __restrict__ Wc, float* __restrict__ cc) {
  const int o = blockIdx.y;
  const int k = blockIdx.x * 256 + threadIdx.x;
  __shared__ float t2[128];
  if (threadIdx.x < 128) {
    const int j = threadIdx.x;
    const float s = g2[j] * rsqrtf(v2[j] + EPSV);
    t2[j] = Wd[o * 128 + j] * s;
  }
  __syncthreads();
  if (k < 512) {
    float accv = 0.f;
    if (k < 500) {
      for (int j = 0; j < 128; ++j) accv += t2[j] * W2[j * 500 + k];
      accv *= 0.5f;
    }
    Wc[o * 512 + k] = f2bf(accv);
  }
  if (blockIdx.x == 0 && threadIdx.x == 0) {
    float accv = bd[o];
    for (int j = 0; j < 128; ++j) {
      const float s = g2[j] * rsqrtf(v2[j] + EPSV);
      accv += Wd[o * 128 + j] * ((b2[j] - m2[j]) * s + be2[j]);
    }
    cc[o] = 0.5f * accv;
  }
}

// ---- CSR build ----
__global__ __launch_bounds__(256) void hist_k(const int* __restrict__ dst,
                                              int* __restrict__ deg, int ne) {
  const int stride = gridDim.x * blockDim.x;
  for (int i = blockIdx.x * blockDim.x + threadIdx.x; i < ne; i += stride)
    atomicAdd(&deg[dst[i]], 1);
}

// multi-block scan: A) per-1024-chunk sums, B) 1-block exclusive scan of
// chunk sums (nb<=128), C) per-chunk rescan + offset -> rp (row starts)
__global__ __launch_bounds__(256) void scanA_k(const int* __restrict__ deg,
                                               int* __restrict__ bsum, int n) {
  const int t = threadIdx.x;
  const int base = blockIdx.x * 1024 + t * 4;
  int s = 0;
  if (base + 3 < n) {
    int4 v = *(const int4*)&deg[base];
    s = v.x + v.y + v.z + v.w;
  } else {
    for (int i = 0; i < 4; ++i) if (base + i < n) s += deg[base + i];
  }
  for (int o = 32; o > 0; o >>= 1) s += __shfl_down(s, o);
  __shared__ int wsum[4];
  if ((t & 63) == 0) wsum[t >> 6] = s;
  __syncthreads();
  if (t == 0) bsum[blockIdx.x] = wsum[0] + wsum[1] + wsum[2] + wsum[3];
}

__global__ __launch_bounds__(128) void scanB_k(int* __restrict__ bsum, int nb) {
  __shared__ int lds[128];
  const int t = threadIdx.x;
  const int v = t < nb ? bsum[t] : 0;
  lds[t] = v;
  __syncthreads();
  for (int o = 1; o < 128; o <<= 1) {
    const int u = t >= o ? lds[t - o] : 0;
    __syncthreads();
    lds[t] += u;
    __syncthreads();
  }
  if (t < nb) bsum[t] = lds[t] - v;  // exclusive
}

__global__ __launch_bounds__(256) void scanC_k(const int* __restrict__ deg,
                                               const int* __restrict__ bsum,
                                               int* __restrict__ rp, int n) {
  const int t = threadIdx.x;
  const int base = blockIdx.x * 1024 + t * 4;
  int v[4];
  int s = 0;
#pragma unroll
  for (int i = 0; i < 4; ++i) {
    v[i] = (base + i < n) ? deg[base + i] : 0;
    s += v[i];
  }
  const int lane = t & 63, w = t >> 6;
  int pre = s;
  for (int o = 1; o < 64; o <<= 1) {
    const int u = __shfl_up(pre, o);
    if (lane >= o) pre += u;
  }
  __shared__ int wsum[4];
  if (lane == 63) wsum[w] = pre;
  __syncthreads();
  int woff = 0;
  for (int i = 0; i < w; ++i) woff += wsum[i];
  int run = bsum[blockIdx.x] + woff + pre - s;
#pragma unroll
  for (int i = 0; i < 4; ++i) {
    if (base + i < n) rp[base + i] = run;
    run += v[i];
  }
}

// rp mutated to end-offsets (start = rp[v] - deg[v] afterwards)
__global__ __launch_bounds__(256) void scatter_k(const int* __restrict__ src,
                                                 const int* __restrict__ dst,
                                                 int* __restrict__ rp,
                                                 int* __restrict__ csr, int ne) {
  const int stride = gridDim.x * blockDim.x;
  for (int i = blockIdx.x * blockDim.x + threadIdx.x; i < ne; i += stride) {
    const int p = atomicAdd(&rp[dst[i]], 1);
    csr[p] = src[i];
  }
}

// per-dst neighbor max: 16 lanes/node, uint2 (4 bf16)/lane; init 0 = DGL
// isolated-node semantics; bf16>=0 compares exactly as u16.
__global__ __launch_bounds__(256) void gather_k(
    const u16* __restrict__ m, const int* __restrict__ csr,
    const int* __restrict__ rpend, const int* __restrict__ deg,
    u16* __restrict__ agg, int n) {
  const int t = threadIdx.x;
  const int v = blockIdx.x * 16 + (t >> 4);
  if (v >= n) return;
  const int l = t & 15;
  const int dg = deg[v];
  const int base = rpend[v] - dg;
  uint2 mx = make_uint2(0u, 0u);
  for (int i = 0; i < dg; ++i) {
    const int u = csr[base + i];
    const uint2 val = *(const uint2*)&m[(size_t)u * 64 + l * 4];
    mx.x = mx2(mx.x, val.x);
    mx.y = mx2(mx.y, val.y);
  }
  *(uint2*)&agg[(size_t)v * 64 + l * 4] = mx;
}

extern "C" void kernel_launch(void* const* d_in, const int* in_sizes, int n_in,
                              void* d_out, int out_size, void* d_ws,
                              size_t ws_size, hipStream_t stream) {
  const int N = 100000;
  const int NE = in_sizes[2];
  const float* x0 = (const float*)d_in[0];
  const float* x1 = (const float*)d_in[1];
  const int* src = (const int*)d_in[2];
  const int* dst = (const int*)d_in[3];
  auto F = [&](int i) { return (const float*)d_in[i]; };

  char* wsb = (char*)d_ws;
  size_t off = 0;
  auto alloc = [&](size_t bytes) {
    void* p = wsb + off;
    off += (bytes + 255) & ~(size_t)255;
    return p;
  };
  u16* W1b0 = (u16*)alloc(500 * 512 * 2);
  u16* W1b1 = (u16*)alloc(500 * 256 * 2);
  u16* Wc0b = (u16*)alloc(64 * 512 * 2);
  u16* Wc1b = (u16*)alloc(64 * 512 * 2);
  float* cc0 = (float*)alloc(64 * 4);
  float* cc1 = (float*)alloc(64 * 4);
  u16* swb[9];
  const int swsrc[9] = {32, 34, 35, 37, 39, 40, 42, 44, 45};
  const int swn[9] = {4096, 4096, 4096, 4096, 4096, 4096, 4096, 512, 512};
  for (int i = 0; i < 9; ++i) swb[i] = (u16*)alloc(swn[i] * 2);
  u16* featb = (u16*)alloc((size_t)N * 64 * 2);
  u16* mb = (u16*)alloc((size_t)N * 64 * 2);
  u16* aggb = (u16*)alloc((size_t)N * 64 * 2);
  u16* h1b = (u16*)alloc((size_t)N * 64 * 2);
  u16* h2b = (u16*)alloc((size_t)N * 64 * 2);
  int* deg = (int*)alloc((size_t)N * 4);
  int* rp = (int*)alloc((size_t)N * 4);
  int* csr = (int*)alloc((size_t)NE * 4);
  const int NB = (N + 1023) / 1024;  // 98 <= 128
  int* bsum = (int*)alloc((size_t)NB * 4);
  // adaptive encoder chunk: E0+E1 cost 2048 B/row
  size_t avail = ws_size > off ? ws_size - off : 0;
  int CH = (int)((avail / 2048) & ~(size_t)127);
  if (CH > N) CH = ((N + 127) & ~127);
  if (CH < 128) CH = 128;  // safety; implies ws too small (won't happen)
  u16* E0 = (u16*)alloc((size_t)CH * 512 * 2);
  u16* E1 = (u16*)alloc((size_t)CH * 512 * 2);
  (void)n_in;

  // weights -> bf16 (one dispatch), combined decode weights
  WConv wc;
  wc.src[0] = F(4);  wc.dst[0] = W1b0; wc.n[0] = 500 * 512;
  wc.src[1] = F(18); wc.dst[1] = W1b1; wc.n[1] = 500 * 256;
  for (int i = 0; i < 9; ++i) {
    wc.src[2 + i] = F(swsrc[i]); wc.dst[2 + i] = swb[i]; wc.n[2 + i] = swn[i];
  }
  wconv_k<<<dim3(64, 11), 256, 0, stream>>>(wc);
  combine_wc<<<dim3(2, 64), 256, 0, stream>>>(F(10), F(11), F(12), F(13), F(14),
                                              F(15), F(16), F(17), Wc0b, cc0);
  combine_wc<<<dim3(2, 64), 256, 0, stream>>>(F(24), F(25), F(26), F(27), F(28),
                                              F(29), F(30), F(31), Wc1b, cc1);

  // CSR build (parallel scan)
  hipMemsetAsync(deg, 0, (size_t)N * 4, stream);
  hist_k<<<512, 256, 0, stream>>>(dst, deg, NE);
  scanA_k<<<NB, 256, 0, stream>>>(deg, bsum, N);
  scanB_k<<<1, 128, 0, stream>>>(bsum, NB);
  scanC_k<<<NB, 256, 0, stream>>>(deg, bsum, rp, N);
  scatter_k<<<512, 256, 0, stream>>>(src, dst, rp, csr, NE);

  // encoders (chunked): E{0,1} = BN(x@W1^T) [fp32 A staged+converted in-GEMM];
  // featb = E0@Wc0^T + E1@Wc1^T + (cc0+cc1)   [one DUAL GEMM]
  for (int r0 = 0; r0 < N; r0 += CH) {
    const int mr = min(CH, N - r0);
    const int gx = (mr + 127) / 128;
    gemm_mfma<128, 2, false, true, false, u16><<<dim3(gx, 4), 256, 0, stream>>>(
        x0 + (size_t)r0 * 512, 512, W1b0, 512, nullptr, nullptr, E0, 512, mr,
        500, 512, 512, nullptr, F(5), F(6), F(7), F(8), F(9));
    gemm_mfma<128, 2, false, true, false, u16><<<dim3(gx, 4), 256, 0, stream>>>(
        x1 + (size_t)r0 * 256, 256, W1b1, 256, nullptr, nullptr, E1, 512, mr,
        500, 256, 512, nullptr, F(19), F(20), F(21), F(22), F(23));
    gemm_mfma<64, 0, true, false, true, u16><<<dim3(gx, 1), 256, 0, stream>>>(
        E0, 512, Wc0b, 512, E1, Wc1b, featb + (size_t)r0 * 64, 64, mr, 64, 512,
        64, cc0, cc1, nullptr, nullptr, nullptr, nullptr);
  }

  // 3 SAGE-pool layers
  const int gx = (N + 127) / 128;
  const int gg = (N + 15) / 16;
  auto sage = [&](const u16* hin, int wi, const float* bp, const float* bb,
                  void* hout, int o, bool relu_out, bool f32out) {
    gemm_mfma<64, 1, false, false, false, u16><<<dim3(gx, 1), 256, 0, stream>>>(
        hin, 64, swb[wi], 64, nullptr, nullptr, mb, 64, N, 64, 64, 64, bp,
        nullptr, nullptr, nullptr, nullptr, nullptr);
    gather_k<<<gg, 256, 0, stream>>>(mb, csr, rp, deg, aggb, N);
    if (f32out)
      gemm_mfma<64, 0, true, false, false, float><<<dim3(gx, 1), 256, 0, stream>>>(
          hin, 64, swb[wi + 1], 64, aggb, swb[wi + 2], hout, o, N, o, 64, o, bb,
          nullptr, nullptr, nullptr, nullptr, nullptr);
    else if (relu_out)
      gemm_mfma<64, 1, true, false, false, u16><<<dim3(gx, 1), 256, 0, stream>>>(
          hin, 64, swb[wi + 1], 64, aggb, swb[wi + 2], hout, o, N, o, 64, o, bb,
          nullptr, nullptr, nullptr, nullptr, nullptr);
  };
  sage(featb, 0, F(33), F(36), h1b, 64, true, false);
  sage(h1b, 3, F(38), F(41), h2b, 64, true, false);
  sage(h2b, 6, F(43), F(46), d_out, 8, false, true);
  (void)out_size;
}

// Round 5
// 706.793 us; speedup vs baseline: 3.8362x; 1.0352x over previous
//
#include <hip/hip_runtime.h>
#include <hip/hip_bf16.h>

#define EPSV 1e-5f
using u16 = unsigned short;
using u32 = unsigned int;
typedef __attribute__((ext_vector_type(8))) short short8;
typedef __attribute__((ext_vector_type(4))) float f32x4;

__device__ __forceinline__ u16 f2bf(float f) {
  __hip_bfloat16 h = __float2bfloat16(f);
  u16 u; __builtin_memcpy(&u, &h, 2); return u;
}

__device__ __forceinline__ void gload16(const void* g, void* l) {
  __builtin_amdgcn_global_load_lds(
      (const __attribute__((address_space(1))) void*)g,
      (__attribute__((address_space(3))) void*)l, 16, 0, 0);
}

// packed 2x u16 max (bf16 >= 0 orders as u16; mask-compare per half)
__device__ __forceinline__ u32 mx2(u32 a, u32 b) {
  u32 ah = a & 0xFFFF0000u, bh = b & 0xFFFF0000u;
  u32 al = a & 0x0000FFFFu, bl = b & 0x0000FFFFu;
  return (ah > bh ? ah : bh) | (al > bl ? al : bl);
}

// ---------------------------------------------------------------------------
// bf16 MFMA NT GEMM: C[M,Nout] = A[M,K] @ B[Nout,K]^T (+ A2@B2^T if DUAL)
// BM=128, BK=64, 256 threads = 4 waves (2x2), wave tile 64 x (BN/2).
// 1-D grid of (gx*nby) blocks. Work index = bijective-XCD remap (m204) of
// blockIdx, decomposed col-tile-fastest: the nby col-tiles sharing an A
// row-block run consecutively on ONE XCD -> A fetched once into its L2 (T1).
// EPI: 0 = +bias; 1 = relu(+bias); 2 = BN epilogue. BIAS2: bias+=bnb[col].
// AF32: A fp32, reg-staged (float4 x2 -> cvt -> swizzled ds_write_b128).
// B (and bf16 A) staged via global_load_lds with pre-swizzled global source;
// swizzle (T2): 16B slot ^= row&7, matched on the ds_read side (rule 21).
// storeN: cols in [Nout,storeN) get 0. K % 64 == 0.
// ---------------------------------------------------------------------------
template <int BN, int EPI, bool DUAL, bool AF32, bool BIAS2, typename OUT>
__global__ __launch_bounds__(256) void gemm_mfma(
    const void* __restrict__ A, int lda, const u16* __restrict__ B, int ldb,
    const u16* __restrict__ A2, const u16* __restrict__ B2, void* __restrict__ C,
    int ldc, int M, int Nout, int K, int storeN, int nby,
    const float* __restrict__ bias, const float* __restrict__ bnb,
    const float* __restrict__ bng, const float* __restrict__ bnbe,
    const float* __restrict__ bnm, const float* __restrict__ bnv) {
  constexpr int WN = BN / 2;   // 64 or 32
  constexpr int NF = WN / 16;  // 4 or 2
  constexpr int MF = 4;
  __shared__ u16 sA[128 * 64];
  __shared__ u16 sB[BN * 64];
  __shared__ u16 sA2[DUAL ? 128 * 64 : 8];
  __shared__ u16 sB2[DUAL ? BN * 64 : 8];

  // bijective XCD remap (m204): orig%8 = XCD; chunk tiles per XCD
  const int nb = gridDim.x;
  const int orig = blockIdx.x;
  const int q = nb >> 3, rr = nb & 7;
  const int xcd = orig & 7, idx = orig >> 3;
  const int wg = (xcd < rr ? xcd * (q + 1) : rr * (q + 1) + (xcd - rr) * q) + idx;
  const int bx = wg / nby;
  const int by = wg % nby;

  const int tid = threadIdx.x;
  const int l = tid & 63;
  const int w = tid >> 6;
  const int wm = w >> 1, wn = w & 1;
  const int row0 = bx * 128;
  const int col0 = by * BN;

  f32x4 acc[MF][NF];
#pragma unroll
  for (int mf = 0; mf < MF; ++mf)
#pragma unroll
    for (int nf = 0; nf < NF; ++nf) acc[mf][nf] = f32x4{0.f, 0.f, 0.f, 0.f};

  const int srl = l >> 3;  // row within wave's 8-row stage group
  const int ssl = l & 7;   // 16B slot within row
  const u16* Ab = (const u16*)A;
  const float* Af = (const float*)A;

  const int ksteps = K >> 6;
  for (int kt = 0; kt < ksteps; ++kt) {
    const int kb = kt * 64;
    // ---- stage A (128 rows x 64 k) ----
    if constexpr (AF32) {
      const int ssl2 = tid & 7;
#pragma unroll
      for (int c = 0; c < 4; ++c) {
        const int r = c * 32 + (tid >> 3);
        const int gr = min(row0 + r, M - 1);
        const float* gp = &Af[(size_t)gr * lda + kb + (ssl2 << 3)];
        float4 f0 = *(const float4*)gp;
        float4 f1 = *(const float4*)(gp + 4);
        short8 pk;
        pk[0] = (short)f2bf(f0.x); pk[1] = (short)f2bf(f0.y);
        pk[2] = (short)f2bf(f0.z); pk[3] = (short)f2bf(f0.w);
        pk[4] = (short)f2bf(f1.x); pk[5] = (short)f2bf(f1.y);
        pk[6] = (short)f2bf(f1.z); pk[7] = (short)f2bf(f1.w);
        *(short8*)&sA[r * 64 + ((ssl2 ^ (r & 7)) << 3)] = pk;
      }
    } else {
#pragma unroll
      for (int c = 0; c < 4; ++c) {
        const int r = c * 32 + w * 8 + srl;
        const int gr = min(row0 + r, M - 1);
        const int gk = kb + ((ssl ^ (r & 7)) << 3);
        gload16(&Ab[(size_t)gr * lda + gk], &sA[(c * 32 + w * 8) * 64]);
        if (DUAL) gload16(&A2[(size_t)gr * lda + gk], &sA2[(c * 32 + w * 8) * 64]);
      }
    }
    // ---- stage B (BN rows x 64 k) ----
#pragma unroll
    for (int c = 0; c < BN / 32; ++c) {
      const int r = c * 32 + w * 8 + srl;
      const int gr = min(col0 + r, Nout - 1);
      const int gk = kb + ((ssl ^ (r & 7)) << 3);
      gload16(&B[(size_t)gr * ldb + gk], &sB[(c * 32 + w * 8) * 64]);
      if (DUAL) gload16(&B2[(size_t)gr * ldb + gk], &sB2[(c * 32 + w * 8) * 64]);
    }
    __syncthreads();
#pragma unroll
    for (int kk = 0; kk < 2; ++kk) {
      short8 af[MF], bfr[NF], af2[MF], bf2[NF];
#pragma unroll
      for (int mf = 0; mf < MF; ++mf) {
        const int r = wm * 64 + mf * 16 + (l & 15);
        const int sl = kk * 4 + (l >> 4);
        const int idx2 = r * 64 + ((sl ^ (r & 7)) << 3);
        af[mf] = *(const short8*)&sA[idx2];
        if (DUAL) af2[mf] = *(const short8*)&sA2[idx2];
      }
#pragma unroll
      for (int nf = 0; nf < NF; ++nf) {
        const int r = wn * WN + nf * 16 + (l & 15);
        const int sl = kk * 4 + (l >> 4);
        const int idx2 = r * 64 + ((sl ^ (r & 7)) << 3);
        bfr[nf] = *(const short8*)&sB[idx2];
        if (DUAL) bf2[nf] = *(const short8*)&sB2[idx2];
      }
#pragma unroll
      for (int mf = 0; mf < MF; ++mf)
#pragma unroll
        for (int nf = 0; nf < NF; ++nf) {
          acc[mf][nf] = __builtin_amdgcn_mfma_f32_16x16x32_bf16(
              af[mf], bfr[nf], acc[mf][nf], 0, 0, 0);
          if (DUAL)
            acc[mf][nf] = __builtin_amdgcn_mfma_f32_16x16x32_bf16(
                af2[mf], bf2[nf], acc[mf][nf], 0, 0, 0);
        }
    }
    __syncthreads();
  }

  // epilogue: D row=(l>>4)*4+j, col=l&15 (m89-verified)
  const int lj = l >> 4;
  const int lc = l & 15;
#pragma unroll
  for (int mf = 0; mf < MF; ++mf)
#pragma unroll
    for (int nf = 0; nf < NF; ++nf) {
      const int col = col0 + wn * WN + nf * 16 + lc;
      if (col >= storeN) continue;
      const bool cok = col < Nout;
      float sc = 0.f, sh = 0.f;
      if (cok) {
        if (EPI == 2) {
          sc = bng[col] * rsqrtf(bnv[col] + EPSV);
          sh = (bnb[col] - bnm[col]) * sc + bnbe[col];
        } else {
          sh = bias[col];
          if (BIAS2) sh += bnb[col];
        }
      }
#pragma unroll
      for (int j = 0; j < 4; ++j) {
        const int row = row0 + wm * 64 + mf * 16 + lj * 4 + j;
        if (row >= M) continue;
        float v = 0.f;
        if (cok) {
          v = acc[mf][nf][j];
          if (EPI == 2) v = v * sc + sh;
          else { v += sh; if (EPI == 1) v = fmaxf(v, 0.f); }
        }
        const size_t idx2 = (size_t)row * ldc + col;
        if constexpr (sizeof(OUT) == 2) ((u16*)C)[idx2] = f2bf(v);
        else ((float*)C)[idx2] = v;
      }
    }
}

// ---- merged fp32->bf16 weight conversion (one dispatch for all tensors) ----
struct WConv {
  const float* src[11];
  u16* dst[11];
  int n[11];
};
__global__ __launch_bounds__(256) void wconv_k(WConv wc) {
  const int t = blockIdx.y;
  const float* in = wc.src[t];
  u16* out = wc.dst[t];
  const int n = wc.n[t];
  const int stride4 = gridDim.x * blockDim.x * 4;
  for (int i4 = (blockIdx.x * blockDim.x + threadIdx.x) * 4; i4 < n; i4 += stride4) {
    float4 f = *(const float4*)&in[i4];
    ushort4 o;
    o.x = f2bf(f.x); o.y = f2bf(f.y); o.z = f2bf(f.z); o.w = f2bf(f.w);
    *(ushort4*)&out[i4] = o;
  }
}

// Combined encoder layer2(Linear+BN)+decoder weight [64,512] (k>=500 zero),
// bf16 out; folds the 0.5 modality mean. cc fp32.
__global__ __launch_bounds__(256) void combine_wc(
    const float* __restrict__ W2, const float* __restrict__ b2,
    const float* __restrict__ g2, const float* __restrict__ be2,
    const float* __restrict__ m2, const float* __restrict__ v2,
    const float* __restrict__ Wd, const float* __restrict__ bd,
    u16* __restrict__ Wc, float* __restrict__ cc) {
  const int o = blockIdx.y;
  const int k = blockIdx.x * 256 + threadIdx.x;
  __shared__ float t2[128];
  if (threadIdx.x < 128) {
    const int j = threadIdx.x;
    const float s = g2[j] * rsqrtf(v2[j] + EPSV);
    t2[j] = Wd[o * 128 + j] * s;
  }
  __syncthreads();
  if (k < 512) {
    float accv = 0.f;
    if (k < 500) {
      for (int j = 0; j < 128; ++j) accv += t2[j] * W2[j * 500 + k];
      accv *= 0.5f;
    }
    Wc[o * 512 + k] = f2bf(accv);
  }
  if (blockIdx.x == 0 && threadIdx.x == 0) {
    float accv = bd[o];
    for (int j = 0; j < 128; ++j) {
      const float s = g2[j] * rsqrtf(v2[j] + EPSV);
      accv += Wd[o * 128 + j] * ((b2[j] - m2[j]) * s + be2[j]);
    }
    cc[o] = 0.5f * accv;
  }
}

// ---- CSR build ----
__global__ __launch_bounds__(256) void hist_k(const int* __restrict__ dst,
                                              int* __restrict__ deg, int ne) {
  const int stride = gridDim.x * blockDim.x;
  for (int i = blockIdx.x * blockDim.x + threadIdx.x; i < ne; i += stride)
    atomicAdd(&deg[dst[i]], 1);
}

// multi-block scan: A) per-1024-chunk sums, B) 1-block exclusive scan of
// chunk sums (nb<=128), C) per-chunk rescan + offset -> rp (row starts)
__global__ __launch_bounds__(256) void scanA_k(const int* __restrict__ deg,
                                               int* __restrict__ bsum, int n) {
  const int t = threadIdx.x;
  const int base = blockIdx.x * 1024 + t * 4;
  int s = 0;
  if (base + 3 < n) {
    int4 v = *(const int4*)&deg[base];
    s = v.x + v.y + v.z + v.w;
  } else {
    for (int i = 0; i < 4; ++i) if (base + i < n) s += deg[base + i];
  }
  for (int o = 32; o > 0; o >>= 1) s += __shfl_down(s, o);
  __shared__ int wsum[4];
  if ((t & 63) == 0) wsum[t >> 6] = s;
  __syncthreads();
  if (t == 0) bsum[blockIdx.x] = wsum[0] + wsum[1] + wsum[2] + wsum[3];
}

__global__ __launch_bounds__(128) void scanB_k(int* __restrict__ bsum, int nb) {
  __shared__ int lds[128];
  const int t = threadIdx.x;
  const int v = t < nb ? bsum[t] : 0;
  lds[t] = v;
  __syncthreads();
  for (int o = 1; o < 128; o <<= 1) {
    const int u = t >= o ? lds[t - o] : 0;
    __syncthreads();
    lds[t] += u;
    __syncthreads();
  }
  if (t < nb) bsum[t] = lds[t] - v;  // exclusive
}

__global__ __launch_bounds__(256) void scanC_k(const int* __restrict__ deg,
                                               const int* __restrict__ bsum,
                                               int* __restrict__ rp, int n) {
  const int t = threadIdx.x;
  const int base = blockIdx.x * 1024 + t * 4;
  int v[4];
  int s = 0;
#pragma unroll
  for (int i = 0; i < 4; ++i) {
    v[i] = (base + i < n) ? deg[base + i] : 0;
    s += v[i];
  }
  const int lane = t & 63, w = t >> 6;
  int pre = s;
  for (int o = 1; o < 64; o <<= 1) {
    const int u = __shfl_up(pre, o);
    if (lane >= o) pre += u;
  }
  __shared__ int wsum[4];
  if (lane == 63) wsum[w] = pre;
  __syncthreads();
  int woff = 0;
  for (int i = 0; i < w; ++i) woff += wsum[i];
  int run = bsum[blockIdx.x] + woff + pre - s;
#pragma unroll
  for (int i = 0; i < 4; ++i) {
    if (base + i < n) rp[base + i] = run;
    run += v[i];
  }
}

// rp mutated to end-offsets (start = rp[v] - deg[v] afterwards)
__global__ __launch_bounds__(256) void scatter_k(const int* __restrict__ src,
                                                 const int* __restrict__ dst,
                                                 int* __restrict__ rp,
                                                 int* __restrict__ csr, int ne) {
  const int stride = gridDim.x * blockDim.x;
  for (int i = blockIdx.x * blockDim.x + threadIdx.x; i < ne; i += stride) {
    const int p = atomicAdd(&rp[dst[i]], 1);
    csr[p] = src[i];
  }
}

// per-dst neighbor max: 16 lanes/node, uint2 (4 bf16)/lane; init 0 = DGL
// isolated-node semantics; bf16>=0 compares exactly as u16.
__global__ __launch_bounds__(256) void gather_k(
    const u16* __restrict__ m, const int* __restrict__ csr,
    const int* __restrict__ rpend, const int* __restrict__ deg,
    u16* __restrict__ agg, int n) {
  const int t = threadIdx.x;
  const int v = blockIdx.x * 16 + (t >> 4);
  if (v >= n) return;
  const int l = t & 15;
  const int dg = deg[v];
  const int base = rpend[v] - dg;
  uint2 mx = make_uint2(0u, 0u);
  for (int i = 0; i < dg; ++i) {
    const int u = csr[base + i];
    const uint2 val = *(const uint2*)&m[(size_t)u * 64 + l * 4];
    mx.x = mx2(mx.x, val.x);
    mx.y = mx2(mx.y, val.y);
  }
  *(uint2*)&agg[(size_t)v * 64 + l * 4] = mx;
}

extern "C" void kernel_launch(void* const* d_in, const int* in_sizes, int n_in,
                              void* d_out, int out_size, void* d_ws,
                              size_t ws_size, hipStream_t stream) {
  const int N = 100000;
  const int NE = in_sizes[2];
  const float* x0 = (const float*)d_in[0];
  const float* x1 = (const float*)d_in[1];
  const int* src = (const int*)d_in[2];
  const int* dst = (const int*)d_in[3];
  auto F = [&](int i) { return (const float*)d_in[i]; };

  char* wsb = (char*)d_ws;
  size_t off = 0;
  auto alloc = [&](size_t bytes) {
    void* p = wsb + off;
    off += (bytes + 255) & ~(size_t)255;
    return p;
  };
  u16* W1b0 = (u16*)alloc(500 * 512 * 2);
  u16* W1b1 = (u16*)alloc(500 * 256 * 2);
  u16* Wc0b = (u16*)alloc(64 * 512 * 2);
  u16* Wc1b = (u16*)alloc(64 * 512 * 2);
  float* cc0 = (float*)alloc(64 * 4);
  float* cc1 = (float*)alloc(64 * 4);
  u16* swb[9];
  const int swsrc[9] = {32, 34, 35, 37, 39, 40, 42, 44, 45};
  const int swn[9] = {4096, 4096, 4096, 4096, 4096, 4096, 4096, 512, 512};
  for (int i = 0; i < 9; ++i) swb[i] = (u16*)alloc(swn[i] * 2);
  u16* featb = (u16*)alloc((size_t)N * 64 * 2);
  u16* mb = (u16*)alloc((size_t)N * 64 * 2);
  u16* aggb = (u16*)alloc((size_t)N * 64 * 2);
  u16* h1b = (u16*)alloc((size_t)N * 64 * 2);
  u16* h2b = (u16*)alloc((size_t)N * 64 * 2);
  int* deg = (int*)alloc((size_t)N * 4);
  int* rp = (int*)alloc((size_t)N * 4);
  int* csr = (int*)alloc((size_t)NE * 4);
  const int NB = (N + 1023) / 1024;  // 98 <= 128
  int* bsum = (int*)alloc((size_t)NB * 4);
  // adaptive encoder chunk: E0+E1 cost 2048 B/row
  size_t avail = ws_size > off ? ws_size - off : 0;
  int CH = (int)((avail / 2048) & ~(size_t)127);
  if (CH > N) CH = ((N + 127) & ~127);
  if (CH < 128) CH = 128;
  u16* E0 = (u16*)alloc((size_t)CH * 512 * 2);
  u16* E1 = (u16*)alloc((size_t)CH * 512 * 2);
  (void)n_in;

  // weights -> bf16 (one dispatch), combined decode weights
  WConv wc;
  wc.src[0] = F(4);  wc.dst[0] = W1b0; wc.n[0] = 500 * 512;
  wc.src[1] = F(18); wc.dst[1] = W1b1; wc.n[1] = 500 * 256;
  for (int i = 0; i < 9; ++i) {
    wc.src[2 + i] = F(swsrc[i]); wc.dst[2 + i] = swb[i]; wc.n[2 + i] = swn[i];
  }
  wconv_k<<<dim3(64, 11), 256, 0, stream>>>(wc);
  combine_wc<<<dim3(2, 64), 256, 0, stream>>>(F(10), F(11), F(12), F(13), F(14),
                                              F(15), F(16), F(17), Wc0b, cc0);
  combine_wc<<<dim3(2, 64), 256, 0, stream>>>(F(24), F(25), F(26), F(27), F(28),
                                              F(29), F(30), F(31), Wc1b, cc1);

  // CSR build (parallel scan)
  hipMemsetAsync(deg, 0, (size_t)N * 4, stream);
  hist_k<<<512, 256, 0, stream>>>(dst, deg, NE);
  scanA_k<<<NB, 256, 0, stream>>>(deg, bsum, N);
  scanB_k<<<1, 128, 0, stream>>>(bsum, NB);
  scanC_k<<<NB, 256, 0, stream>>>(deg, bsum, rp, N);
  scatter_k<<<512, 256, 0, stream>>>(src, dst, rp, csr, NE);

  // encoders (chunked): E{0,1} = BN(x@W1^T) [fp32 A staged+converted in-GEMM];
  // featb = E0@Wc0^T + E1@Wc1^T + (cc0+cc1)   [one DUAL GEMM]
  for (int r0 = 0; r0 < N; r0 += CH) {
    const int mr = min(CH, N - r0);
    const int gx = (mr + 127) / 128;
    gemm_mfma<128, 2, false, true, false, u16><<<gx * 4, 256, 0, stream>>>(
        x0 + (size_t)r0 * 512, 512, W1b0, 512, nullptr, nullptr, E0, 512, mr,
        500, 512, 512, 4, nullptr, F(5), F(6), F(7), F(8), F(9));
    gemm_mfma<128, 2, false, true, false, u16><<<gx * 4, 256, 0, stream>>>(
        x1 + (size_t)r0 * 256, 256, W1b1, 256, nullptr, nullptr, E1, 512, mr,
        500, 256, 512, 4, nullptr, F(19), F(20), F(21), F(22), F(23));
    gemm_mfma<64, 0, true, false, true, u16><<<gx, 256, 0, stream>>>(
        E0, 512, Wc0b, 512, E1, Wc1b, featb + (size_t)r0 * 64, 64, mr, 64, 512,
        64, 1, cc0, cc1, nullptr, nullptr, nullptr, nullptr);
  }

  // 3 SAGE-pool layers
  const int gx = (N + 127) / 128;
  const int gg = (N + 15) / 16;
  auto sage = [&](const u16* hin, int wi, const float* bp, const float* bb,
                  void* hout, int o, bool relu_out, bool f32out) {
    gemm_mfma<64, 1, false, false, false, u16><<<gx, 256, 0, stream>>>(
        hin, 64, swb[wi], 64, nullptr, nullptr, mb, 64, N, 64, 64, 64, 1, bp,
        nullptr, nullptr, nullptr, nullptr, nullptr);
    gather_k<<<gg, 256, 0, stream>>>(mb, csr, rp, deg, aggb, N);
    if (f32out)
      gemm_mfma<64, 0, true, false, false, float><<<gx, 256, 0, stream>>>(
          hin, 64, swb[wi + 1], 64, aggb, swb[wi + 2], hout, o, N, o, 64, o, 1,
          bb, nullptr, nullptr, nullptr, nullptr, nullptr);
    else if (relu_out)
      gemm_mfma<64, 1, true, false, false, u16><<<gx, 256, 0, stream>>>(
          hin, 64, swb[wi + 1], 64, aggb, swb[wi + 2], hout, o, N, o, 64, o, 1,
          bb, nullptr, nullptr, nullptr, nullptr, nullptr);
  };
  sage(featb, 0, F(33), F(36), h1b, 64, true, false);
  sage(h1b, 3, F(38), F(41), h2b, 64, true, false);
  sage(h2b, 6, F(43), F(46), d_out, 8, false, true);
  (void)out_size;
}

// Round 6
// 639.655 us; speedup vs baseline: 4.2388x; 1.1050x over previous
//
#include <hip/hip_runtime.h>
#include <hip/hip_bf16.h>

#define EPSV 1e-5f
using u16 = unsigned short;
using u32 = unsigned int;
typedef __attribute__((ext_vector_type(8))) short short8;
typedef __attribute__((ext_vector_type(4))) float f32x4;

__device__ __forceinline__ u16 f2bf(float f) {
  __hip_bfloat16 h = __float2bfloat16(f);
  u16 u; __builtin_memcpy(&u, &h, 2); return u;
}

__device__ __forceinline__ void gload16(const void* g, void* l) {
  __builtin_amdgcn_global_load_lds(
      (const __attribute__((address_space(1))) void*)g,
      (__attribute__((address_space(3))) void*)l, 16, 0, 0);
}

// packed 2x u16 max (bf16 >= 0 orders as u16; mask-compare per half)
__device__ __forceinline__ u32 mx2(u32 a, u32 b) {
  u32 ah = a & 0xFFFF0000u, bh = b & 0xFFFF0000u;
  u32 al = a & 0x0000FFFFu, bl = b & 0x0000FFFFu;
  return (ah > bh ? ah : bh) | (al > bl ? al : bl);
}

// ---------------------------------------------------------------------------
// Fully-collapsed encoder GEMM:
//   featb[M,64] = bf16( x0[M,512] @ Weff0[64,512]^T
//                     + x1[M,256] @ Weff1[64,256]^T + beff0 + beff1 )
// 12 K-steps of 64 (8 from x0, 4 from x1) into ONE accumulator.
// 256 thr = 4 waves (2x2), wave tile 64x32. Reg-prefetch one K-step ahead
// (named even/odd reg sets -> no runtime-indexed arrays, rule 20), single
// LDS buffer (24 KB), swizzled ds_write/ds_read (T2, both sides, rule 21).
// ---------------------------------------------------------------------------
struct EncReg { float4 a[8]; short8 b[2]; };

__global__ __launch_bounds__(256) void enc_gemm(
    const float* __restrict__ x0, const float* __restrict__ x1,
    const u16* __restrict__ W0, const u16* __restrict__ W1,
    const float* __restrict__ beff0, const float* __restrict__ beff1,
    u16* __restrict__ out, int M) {
  __shared__ u16 sA[128 * 64];
  __shared__ u16 sB[64 * 64];
  const int tid = threadIdx.x;
  const int l = tid & 63;
  const int w = tid >> 6;
  const int wm = w >> 1, wn = w & 1;
  const int row0 = blockIdx.x * 128;

  f32x4 acc[4][2];
#pragma unroll
  for (int mf = 0; mf < 4; ++mf)
#pragma unroll
    for (int nf = 0; nf < 2; ++nf) acc[mf][nf] = f32x4{0.f, 0.f, 0.f, 0.f};

  auto loadstep = [&](EncReg& rs, int s) {
    const int ph = s >= 8;
    const float* X = ph ? x1 : x0;
    const u16* W = ph ? W1 : W0;
    const int lda = ph ? 256 : 512;
    const int kb = (s - (ph ? 8 : 0)) * 64;
#pragma unroll
    for (int c = 0; c < 4; ++c) {
      const int r = c * 32 + (tid >> 3);
      const int gr = min(row0 + r, M - 1);
      const float* gp = &X[(size_t)gr * lda + kb + ((tid & 7) << 3)];
      rs.a[c * 2] = *(const float4*)gp;
      rs.a[c * 2 + 1] = *(const float4*)(gp + 4);
    }
#pragma unroll
    for (int i = 0; i < 2; ++i) {
      const int s2 = tid * 2 + i;
      const int rb = s2 >> 3, sl = s2 & 7;
      rs.b[i] = *(const short8*)&W[rb * lda + kb + sl * 8];
    }
  };
  auto storestep = [&](const EncReg& rs) {
#pragma unroll
    for (int c = 0; c < 4; ++c) {
      const int r = c * 32 + (tid >> 3);
      const int ssl = tid & 7;
      short8 pk;
#pragma unroll
      for (int j = 0; j < 4; ++j) pk[j] = (short)f2bf(rs.a[c * 2][j]);
#pragma unroll
      for (int j = 0; j < 4; ++j) pk[4 + j] = (short)f2bf(rs.a[c * 2 + 1][j]);
      *(short8*)&sA[r * 64 + ((ssl ^ (r & 7)) << 3)] = pk;
    }
#pragma unroll
    for (int i = 0; i < 2; ++i) {
      const int s2 = tid * 2 + i;
      const int rb = s2 >> 3, sl = s2 & 7;
      *(short8*)&sB[rb * 64 + ((sl ^ (rb & 7)) << 3)] = rs.b[i];
    }
  };
  auto compute = [&]() {
#pragma unroll
    for (int kk = 0; kk < 2; ++kk) {
      short8 af[4], bf[2];
#pragma unroll
      for (int mf = 0; mf < 4; ++mf) {
        const int r = wm * 64 + mf * 16 + (l & 15);
        const int sl = kk * 4 + (l >> 4);
        af[mf] = *(const short8*)&sA[r * 64 + ((sl ^ (r & 7)) << 3)];
      }
#pragma unroll
      for (int nf = 0; nf < 2; ++nf) {
        const int r = wn * 32 + nf * 16 + (l & 15);
        const int sl = kk * 4 + (l >> 4);
        bf[nf] = *(const short8*)&sB[r * 64 + ((sl ^ (r & 7)) << 3)];
      }
#pragma unroll
      for (int mf = 0; mf < 4; ++mf)
#pragma unroll
        for (int nf = 0; nf < 2; ++nf)
          acc[mf][nf] = __builtin_amdgcn_mfma_f32_16x16x32_bf16(
              af[mf], bf[nf], acc[mf][nf], 0, 0, 0);
    }
  };

  EncReg rA, rB;
  loadstep(rA, 0);
  for (int s = 0; s < 12; s += 2) {
    loadstep(rB, s + 1);               // prefetch odd step
    storestep(rA);
    __syncthreads();
    compute();
    __syncthreads();
    if (s + 2 < 12) loadstep(rA, s + 2);  // prefetch next even step
    storestep(rB);
    __syncthreads();
    compute();
    __syncthreads();
  }

  const int lj = l >> 4, lc = l & 15;
#pragma unroll
  for (int mf = 0; mf < 4; ++mf)
#pragma unroll
    for (int nf = 0; nf < 2; ++nf) {
      const int col = wn * 32 + nf * 16 + lc;
      const float sh = beff0[col] + beff1[col];
#pragma unroll
      for (int j = 0; j < 4; ++j) {
        const int row = row0 + wm * 64 + mf * 16 + lj * 4 + j;
        if (row >= M) continue;
        out[(size_t)row * 64 + col] = f2bf(acc[mf][nf][j] + sh);
      }
    }
}

// ---------------------------------------------------------------------------
// bf16 MFMA NT GEMM (SAGE layers): C = A@B^T (+A2@B2^T). Same proven kernel
// as round 5 (BM=128, BK=64, XCD-remap 1-D grid, T2 swizzle both-sides).
// ---------------------------------------------------------------------------
template <int BN, int EPI, bool DUAL, bool AF32, bool BIAS2, typename OUT>
__global__ __launch_bounds__(256) void gemm_mfma(
    const void* __restrict__ A, int lda, const u16* __restrict__ B, int ldb,
    const u16* __restrict__ A2, const u16* __restrict__ B2, void* __restrict__ C,
    int ldc, int M, int Nout, int K, int storeN, int nby,
    const float* __restrict__ bias, const float* __restrict__ bnb,
    const float* __restrict__ bng, const float* __restrict__ bnbe,
    const float* __restrict__ bnm, const float* __restrict__ bnv) {
  constexpr int WN = BN / 2;
  constexpr int NF = WN / 16;
  constexpr int MF = 4;
  __shared__ u16 sA[128 * 64];
  __shared__ u16 sB[BN * 64];
  __shared__ u16 sA2[DUAL ? 128 * 64 : 8];
  __shared__ u16 sB2[DUAL ? BN * 64 : 8];

  const int nb = gridDim.x;
  const int orig = blockIdx.x;
  const int q = nb >> 3, rr = nb & 7;
  const int xcd = orig & 7, idx = orig >> 3;
  const int wg = (xcd < rr ? xcd * (q + 1) : rr * (q + 1) + (xcd - rr) * q) + idx;
  const int bx = wg / nby;
  const int by = wg % nby;

  const int tid = threadIdx.x;
  const int l = tid & 63;
  const int w = tid >> 6;
  const int wm = w >> 1, wn = w & 1;
  const int row0 = bx * 128;
  const int col0 = by * BN;

  f32x4 acc[MF][NF];
#pragma unroll
  for (int mf = 0; mf < MF; ++mf)
#pragma unroll
    for (int nf = 0; nf < NF; ++nf) acc[mf][nf] = f32x4{0.f, 0.f, 0.f, 0.f};

  const int srl = l >> 3;
  const int ssl = l & 7;
  const u16* Ab = (const u16*)A;
  const float* Af = (const float*)A;

  const int ksteps = K >> 6;
  for (int kt = 0; kt < ksteps; ++kt) {
    const int kb = kt * 64;
    if constexpr (AF32) {
      const int ssl2 = tid & 7;
#pragma unroll
      for (int c = 0; c < 4; ++c) {
        const int r = c * 32 + (tid >> 3);
        const int gr = min(row0 + r, M - 1);
        const float* gp = &Af[(size_t)gr * lda + kb + (ssl2 << 3)];
        float4 f0 = *(const float4*)gp;
        float4 f1 = *(const float4*)(gp + 4);
        short8 pk;
        pk[0] = (short)f2bf(f0.x); pk[1] = (short)f2bf(f0.y);
        pk[2] = (short)f2bf(f0.z); pk[3] = (short)f2bf(f0.w);
        pk[4] = (short)f2bf(f1.x); pk[5] = (short)f2bf(f1.y);
        pk[6] = (short)f2bf(f1.z); pk[7] = (short)f2bf(f1.w);
        *(short8*)&sA[r * 64 + ((ssl2 ^ (r & 7)) << 3)] = pk;
      }
    } else {
#pragma unroll
      for (int c = 0; c < 4; ++c) {
        const int r = c * 32 + w * 8 + srl;
        const int gr = min(row0 + r, M - 1);
        const int gk = kb + ((ssl ^ (r & 7)) << 3);
        gload16(&Ab[(size_t)gr * lda + gk], &sA[(c * 32 + w * 8) * 64]);
        if (DUAL) gload16(&A2[(size_t)gr * lda + gk], &sA2[(c * 32 + w * 8) * 64]);
      }
    }
#pragma unroll
    for (int c = 0; c < BN / 32; ++c) {
      const int r = c * 32 + w * 8 + srl;
      const int gr = min(col0 + r, Nout - 1);
      const int gk = kb + ((ssl ^ (r & 7)) << 3);
      gload16(&B[(size_t)gr * ldb + gk], &sB[(c * 32 + w * 8) * 64]);
      if (DUAL) gload16(&B2[(size_t)gr * ldb + gk], &sB2[(c * 32 + w * 8) * 64]);
    }
    __syncthreads();
#pragma unroll
    for (int kk = 0; kk < 2; ++kk) {
      short8 af[MF], bfr[NF], af2[MF], bf2[NF];
#pragma unroll
      for (int mf = 0; mf < MF; ++mf) {
        const int r = wm * 64 + mf * 16 + (l & 15);
        const int sl = kk * 4 + (l >> 4);
        const int idx2 = r * 64 + ((sl ^ (r & 7)) << 3);
        af[mf] = *(const short8*)&sA[idx2];
        if (DUAL) af2[mf] = *(const short8*)&sA2[idx2];
      }
#pragma unroll
      for (int nf = 0; nf < NF; ++nf) {
        const int r = wn * WN + nf * 16 + (l & 15);
        const int sl = kk * 4 + (l >> 4);
        const int idx2 = r * 64 + ((sl ^ (r & 7)) << 3);
        bfr[nf] = *(const short8*)&sB[idx2];
        if (DUAL) bf2[nf] = *(const short8*)&sB2[idx2];
      }
#pragma unroll
      for (int mf = 0; mf < MF; ++mf)
#pragma unroll
        for (int nf = 0; nf < NF; ++nf) {
          acc[mf][nf] = __builtin_amdgcn_mfma_f32_16x16x32_bf16(
              af[mf], bfr[nf], acc[mf][nf], 0, 0, 0);
          if (DUAL)
            acc[mf][nf] = __builtin_amdgcn_mfma_f32_16x16x32_bf16(
                af2[mf], bf2[nf], acc[mf][nf], 0, 0, 0);
        }
    }
    __syncthreads();
  }

  const int lj = l >> 4;
  const int lc = l & 15;
#pragma unroll
  for (int mf = 0; mf < MF; ++mf)
#pragma unroll
    for (int nf = 0; nf < NF; ++nf) {
      const int col = col0 + wn * WN + nf * 16 + lc;
      if (col >= storeN) continue;
      const bool cok = col < Nout;
      float sc = 0.f, sh = 0.f;
      if (cok) {
        if (EPI == 2) {
          sc = bng[col] * rsqrtf(bnv[col] + EPSV);
          sh = (bnb[col] - bnm[col]) * sc + bnbe[col];
        } else {
          sh = bias[col];
          if (BIAS2) sh += bnb[col];
        }
      }
#pragma unroll
      for (int j = 0; j < 4; ++j) {
        const int row = row0 + wm * 64 + mf * 16 + lj * 4 + j;
        if (row >= M) continue;
        float v = 0.f;
        if (cok) {
          v = acc[mf][nf][j];
          if (EPI == 2) v = v * sc + sh;
          else { v += sh; if (EPI == 1) v = fmaxf(v, 0.f); }
        }
        const size_t idx2 = (size_t)row * ldc + col;
        if constexpr (sizeof(OUT) == 2) ((u16*)C)[idx2] = f2bf(v);
        else ((float*)C)[idx2] = v;
      }
    }
}

// ---- merged fp32->bf16 weight conversion (sage weights) ----
struct WConv {
  const float* src[9];
  u16* dst[9];
  int n[9];
};
__global__ __launch_bounds__(256) void wconv_k(WConv wc) {
  const int t = blockIdx.y;
  const float* in = wc.src[t];
  u16* out = wc.dst[t];
  const int n = wc.n[t];
  const int stride4 = gridDim.x * blockDim.x * 4;
  for (int i4 = (blockIdx.x * blockDim.x + threadIdx.x) * 4; i4 < n; i4 += stride4) {
    float4 f = *(const float4*)&in[i4];
    ushort4 o;
    o.x = f2bf(f.x); o.y = f2bf(f.y); o.z = f2bf(f.z); o.w = f2bf(f.w);
    *(ushort4*)&out[i4] = o;
  }
}

// fp32 combined layer2(Linear+BN)+decoder weight [64,500] (0.5 folded) + cc
__global__ __launch_bounds__(256) void combine_wcf(
    const float* __restrict__ W2, const float* __restrict__ b2,
    const float* __restrict__ g2, const float* __restrict__ be2,
    const float* __restrict__ m2, const float* __restrict__ v2,
    const float* __restrict__ Wd, const float* __restrict__ bd,
    float* __restrict__ Wcf, float* __restrict__ cc) {
  const int o = blockIdx.y;
  const int k = blockIdx.x * 256 + threadIdx.x;
  __shared__ float t2[128];
  if (threadIdx.x < 128) {
    const int j = threadIdx.x;
    const float s = g2[j] * rsqrtf(v2[j] + EPSV);
    t2[j] = Wd[o * 128 + j] * s;
  }
  __syncthreads();
  if (k < 500) {
    float accv = 0.f;
    for (int j = 0; j < 128; ++j) accv += t2[j] * W2[j * 500 + k];
    Wcf[o * 500 + k] = 0.5f * accv;
  }
  if (blockIdx.x == 0 && threadIdx.x == 0) {
    float accv = bd[o];
    for (int j = 0; j < 128; ++j) {
      const float s = g2[j] * rsqrtf(v2[j] + EPSV);
      accv += Wd[o * 128 + j] * ((b2[j] - m2[j]) * s + be2[j]);
    }
    cc[o] = 0.5f * accv;
  }
}

// Collapse layer1+BN1 into Weff[o,d] = sum_j Wcf[o,j]*s1[j]*W1[j,d] (bf16 out)
// and beff[o] = sum_j t1[j]*Wcf[o,j] + cc[o]. One block per o.
__global__ __launch_bounds__(256) void weff_k(
    const float* __restrict__ Wcf, const float* __restrict__ cc,
    const float* __restrict__ g1, const float* __restrict__ be1,
    const float* __restrict__ b1, const float* __restrict__ m1,
    const float* __restrict__ v1, const float* __restrict__ W1, int D,
    u16* __restrict__ Weffb, float* __restrict__ beff) {
  const int o = blockIdx.x;
  const int t = threadIdx.x;
  __shared__ float wcs[500];
  __shared__ float red[256];
  float pb = 0.f;
  for (int j = t; j < 500; j += 256) {
    const float wc = Wcf[o * 500 + j];
    const float s = g1[j] * rsqrtf(v1[j] + EPSV);
    wcs[j] = wc * s;
    pb += wc * ((b1[j] - m1[j]) * s + be1[j]);
  }
  red[t] = pb;
  __syncthreads();
  for (int off2 = 128; off2 > 0; off2 >>= 1) {
    if (t < off2) red[t] += red[t + off2];
    __syncthreads();
  }
  if (t == 0) beff[o] = red[0] + cc[o];
  for (int d = t; d < D; d += 256) {
    float accv = 0.f;
    for (int j = 0; j < 500; ++j) accv += wcs[j] * W1[(size_t)j * D + d];
    Weffb[o * D + d] = f2bf(accv);
  }
}

// ---- CSR build ----
__global__ __launch_bounds__(256) void hist_k(const int* __restrict__ dst,
                                              int* __restrict__ deg, int ne) {
  const int stride = gridDim.x * blockDim.x;
  for (int i = blockIdx.x * blockDim.x + threadIdx.x; i < ne; i += stride)
    atomicAdd(&deg[dst[i]], 1);
}

__global__ __launch_bounds__(256) void scanA_k(const int* __restrict__ deg,
                                               int* __restrict__ bsum, int n) {
  const int t = threadIdx.x;
  const int base = blockIdx.x * 1024 + t * 4;
  int s = 0;
  if (base + 3 < n) {
    int4 v = *(const int4*)&deg[base];
    s = v.x + v.y + v.z + v.w;
  } else {
    for (int i = 0; i < 4; ++i) if (base + i < n) s += deg[base + i];
  }
  for (int o = 32; o > 0; o >>= 1) s += __shfl_down(s, o);
  __shared__ int wsum[4];
  if ((t & 63) == 0) wsum[t >> 6] = s;
  __syncthreads();
  if (t == 0) bsum[blockIdx.x] = wsum[0] + wsum[1] + wsum[2] + wsum[3];
}

__global__ __launch_bounds__(128) void scanB_k(int* __restrict__ bsum, int nb) {
  __shared__ int lds[128];
  const int t = threadIdx.x;
  const int v = t < nb ? bsum[t] : 0;
  lds[t] = v;
  __syncthreads();
  for (int o = 1; o < 128; o <<= 1) {
    const int u = t >= o ? lds[t - o] : 0;
    __syncthreads();
    lds[t] += u;
    __syncthreads();
  }
  if (t < nb) bsum[t] = lds[t] - v;
}

__global__ __launch_bounds__(256) void scanC_k(const int* __restrict__ deg,
                                               const int* __restrict__ bsum,
                                               int* __restrict__ rp, int n) {
  const int t = threadIdx.x;
  const int base = blockIdx.x * 1024 + t * 4;
  int v[4];
  int s = 0;
#pragma unroll
  for (int i = 0; i < 4; ++i) {
    v[i] = (base + i < n) ? deg[base + i] : 0;
    s += v[i];
  }
  const int lane = t & 63, w = t >> 6;
  int pre = s;
  for (int o = 1; o < 64; o <<= 1) {
    const int u = __shfl_up(pre, o);
    if (lane >= o) pre += u;
  }
  __shared__ int wsum[4];
  if (lane == 63) wsum[w] = pre;
  __syncthreads();
  int woff = 0;
  for (int i = 0; i < w; ++i) woff += wsum[i];
  int run = bsum[blockIdx.x] + woff + pre - s;
#pragma unroll
  for (int i = 0; i < 4; ++i) {
    if (base + i < n) rp[base + i] = run;
    run += v[i];
  }
}

__global__ __launch_bounds__(256) void scatter_k(const int* __restrict__ src,
                                                 const int* __restrict__ dst,
                                                 int* __restrict__ rp,
                                                 int* __restrict__ csr, int ne) {
  const int stride = gridDim.x * blockDim.x;
  for (int i = blockIdx.x * blockDim.x + threadIdx.x; i < ne; i += stride) {
    const int p = atomicAdd(&rp[dst[i]], 1);
    csr[p] = src[i];
  }
}

// per-dst neighbor max: 16 lanes/node, uint2 (4 bf16)/lane
__global__ __launch_bounds__(256) void gather_k(
    const u16* __restrict__ m, const int* __restrict__ csr,
    const int* __restrict__ rpend, const int* __restrict__ deg,
    u16* __restrict__ agg, int n) {
  const int t = threadIdx.x;
  const int v = blockIdx.x * 16 + (t >> 4);
  if (v >= n) return;
  const int l = t & 15;
  const int dg = deg[v];
  const int base = rpend[v] - dg;
  uint2 mx = make_uint2(0u, 0u);
  for (int i = 0; i < dg; ++i) {
    const int u = csr[base + i];
    const uint2 val = *(const uint2*)&m[(size_t)u * 64 + l * 4];
    mx.x = mx2(mx.x, val.x);
    mx.y = mx2(mx.y, val.y);
  }
  *(uint2*)&agg[(size_t)v * 64 + l * 4] = mx;
}

extern "C" void kernel_launch(void* const* d_in, const int* in_sizes, int n_in,
                              void* d_out, int out_size, void* d_ws,
                              size_t ws_size, hipStream_t stream) {
  const int N = 100000;
  const int NE = in_sizes[2];
  const float* x0 = (const float*)d_in[0];
  const float* x1 = (const float*)d_in[1];
  const int* src = (const int*)d_in[2];
  const int* dst = (const int*)d_in[3];
  auto F = [&](int i) { return (const float*)d_in[i]; };

  char* wsb = (char*)d_ws;
  size_t off = 0;
  auto alloc = [&](size_t bytes) {
    void* p = wsb + off;
    off += (bytes + 255) & ~(size_t)255;
    return p;
  };
  float* Wcf0 = (float*)alloc(64 * 500 * 4);
  float* Wcf1 = (float*)alloc(64 * 500 * 4);
  float* cc0 = (float*)alloc(64 * 4);
  float* cc1 = (float*)alloc(64 * 4);
  u16* Weff0b = (u16*)alloc(64 * 512 * 2);
  u16* Weff1b = (u16*)alloc(64 * 256 * 2);
  float* beff0 = (float*)alloc(64 * 4);
  float* beff1 = (float*)alloc(64 * 4);
  u16* swb[9];
  const int swsrc[9] = {32, 34, 35, 37, 39, 40, 42, 44, 45};
  const int swn[9] = {4096, 4096, 4096, 4096, 4096, 4096, 4096, 512, 512};
  for (int i = 0; i < 9; ++i) swb[i] = (u16*)alloc(swn[i] * 2);
  u16* featb = (u16*)alloc((size_t)N * 64 * 2);
  u16* mb = (u16*)alloc((size_t)N * 64 * 2);
  u16* aggb = (u16*)alloc((size_t)N * 64 * 2);
  u16* h1b = (u16*)alloc((size_t)N * 64 * 2);
  u16* h2b = (u16*)alloc((size_t)N * 64 * 2);
  int* deg = (int*)alloc((size_t)N * 4);
  int* rp = (int*)alloc((size_t)N * 4);
  int* csr = (int*)alloc((size_t)NE * 4);
  const int NB = (N + 1023) / 1024;  // 98 <= 128
  int* bsum = (int*)alloc((size_t)NB * 4);
  (void)n_in; (void)ws_size;

  // weight prep: sage weights -> bf16; encoder fully collapsed to Weff/beff
  WConv wc;
  for (int i = 0; i < 9; ++i) {
    wc.src[i] = F(swsrc[i]); wc.dst[i] = swb[i]; wc.n[i] = swn[i];
  }
  wconv_k<<<dim3(8, 9), 256, 0, stream>>>(wc);
  combine_wcf<<<dim3(2, 64), 256, 0, stream>>>(F(10), F(11), F(12), F(13),
                                               F(14), F(15), F(16), F(17),
                                               Wcf0, cc0);
  combine_wcf<<<dim3(2, 64), 256, 0, stream>>>(F(24), F(25), F(26), F(27),
                                               F(28), F(29), F(30), F(31),
                                               Wcf1, cc1);
  weff_k<<<64, 256, 0, stream>>>(Wcf0, cc0, F(6), F(7), F(5), F(8), F(9),
                                 F(4), 512, Weff0b, beff0);
  weff_k<<<64, 256, 0, stream>>>(Wcf1, cc1, F(20), F(21), F(19), F(22), F(23),
                                 F(18), 256, Weff1b, beff1);

  // CSR build (parallel scan)
  hipMemsetAsync(deg, 0, (size_t)N * 4, stream);
  hist_k<<<512, 256, 0, stream>>>(dst, deg, NE);
  scanA_k<<<NB, 256, 0, stream>>>(deg, bsum, N);
  scanB_k<<<1, 128, 0, stream>>>(bsum, NB);
  scanC_k<<<NB, 256, 0, stream>>>(deg, bsum, rp, N);
  scatter_k<<<512, 256, 0, stream>>>(src, dst, rp, csr, NE);

  // collapsed encoder: one HBM-bound pass over x0 and x1
  enc_gemm<<<(N + 127) / 128, 256, 0, stream>>>(x0, x1, Weff0b, Weff1b, beff0,
                                                beff1, featb, N);

  // 3 SAGE-pool layers (unchanged)
  const int gx = (N + 127) / 128;
  const int gg = (N + 15) / 16;
  auto sage = [&](const u16* hin, int wi, const float* bp, const float* bb,
                  void* hout, int o, bool relu_out, bool f32out) {
    gemm_mfma<64, 1, false, false, false, u16><<<gx, 256, 0, stream>>>(
        hin, 64, swb[wi], 64, nullptr, nullptr, mb, 64, N, 64, 64, 64, 1, bp,
        nullptr, nullptr, nullptr, nullptr, nullptr);
    gather_k<<<gg, 256, 0, stream>>>(mb, csr, rp, deg, aggb, N);
    if (f32out)
      gemm_mfma<64, 0, true, false, false, float><<<gx, 256, 0, stream>>>(
          hin, 64, swb[wi + 1], 64, aggb, swb[wi + 2], hout, o, N, o, 64, o, 1,
          bb, nullptr, nullptr, nullptr, nullptr, nullptr);
    else if (relu_out)
      gemm_mfma<64, 1, true, false, false, u16><<<gx, 256, 0, stream>>>(
          hin, 64, swb[wi + 1], 64, aggb, swb[wi + 2], hout, o, N, o, 64, o, 1,
          bb, nullptr, nullptr, nullptr, nullptr, nullptr);
  };
  sage(featb, 0, F(33), F(36), h1b, 64, true, false);
  sage(h1b, 3, F(38), F(41), h2b, 64, true, false);
  sage(h2b, 6, F(43), F(46), d_out, 8, false, true);
  (void)out_size;
}